// Round 2
// baseline (1755.392 us; speedup 1.0000x reference)
//
#include <hip/hip_runtime.h>
#include <math.h>

// ---------------------------------------------------------------------------
// BasedBlock: B=4 L=2048 d=1024 h=16 f=16 hd=64 w=64, D=1+f+f*f=273
// Round 1: fix k_new output offset (was writing past out_size; real k_new
// region stayed zero). No kernel changes — out & kv_new already passed.
// ---------------------------------------------------------------------------

#define LL 2048
#define DD 1024
#define HH 16
#define FF 16
#define HD 64
#define DFEAT 273
#define NC 16
#define CHUNK 128

__device__ __forceinline__ float4 f4(float a, float b, float c, float d) {
  float4 r; r.x = a; r.y = b; r.z = c; r.w = d; return r;
}

// ------------------------------ GEMM ---------------------------------------
// C[M,N] = A[M,K] @ W[K,N] + bias[N].  M%128==0, N%128==0, K%16==0.
__global__ __launch_bounds__(256) void gemm_bias(
    const float* __restrict__ A, const float* __restrict__ W,
    const float* __restrict__ bias, float* __restrict__ C,
    int M, int N, int K) {
  __shared__ float As[16][128];
  __shared__ float Bs[16][128];
  const int tid = threadIdx.x;
  const int row0 = blockIdx.x * 128, col0 = blockIdx.y * 128;
  const int tx = tid & 15, ty = tid >> 4;
  const int am = tid >> 1, ak = (tid & 1) * 8;
  const int bk = tid >> 4, bn8 = (tid & 15) * 8;
  float acc[8][8] = {};
  for (int k0 = 0; k0 < K; k0 += 16) {
    const float* ap = A + (size_t)(row0 + am) * K + k0 + ak;
    float4 a0 = *(const float4*)ap;
    float4 a1 = *(const float4*)(ap + 4);
    As[ak + 0][am] = a0.x; As[ak + 1][am] = a0.y;
    As[ak + 2][am] = a0.z; As[ak + 3][am] = a0.w;
    As[ak + 4][am] = a1.x; As[ak + 5][am] = a1.y;
    As[ak + 6][am] = a1.z; As[ak + 7][am] = a1.w;
    const float* bp = W + (size_t)(k0 + bk) * N + col0 + bn8;
    *(float4*)&Bs[bk][bn8] = *(const float4*)bp;
    *(float4*)&Bs[bk][bn8 + 4] = *(const float4*)(bp + 4);
    __syncthreads();
#pragma unroll
    for (int kk = 0; kk < 16; ++kk) {
      float4 av0 = *(const float4*)&As[kk][ty * 8];
      float4 av1 = *(const float4*)&As[kk][ty * 8 + 4];
      float4 bv0 = *(const float4*)&Bs[kk][tx * 8];
      float4 bv1 = *(const float4*)&Bs[kk][tx * 8 + 4];
      float a[8] = {av0.x, av0.y, av0.z, av0.w, av1.x, av1.y, av1.z, av1.w};
      float b[8] = {bv0.x, bv0.y, bv0.z, bv0.w, bv1.x, bv1.y, bv1.z, bv1.w};
#pragma unroll
      for (int i = 0; i < 8; i++)
#pragma unroll
        for (int j = 0; j < 8; j++) acc[i][j] = fmaf(a[i], b[j], acc[i][j]);
    }
    __syncthreads();
  }
#pragma unroll
  for (int i = 0; i < 8; i++) {
    float* cp = C + (size_t)(row0 + ty * 8 + i) * N + col0 + tx * 8;
    const float* bb = bias + col0 + tx * 8;
    *(float4*)cp = f4(acc[i][0] + bb[0], acc[i][1] + bb[1],
                      acc[i][2] + bb[2], acc[i][3] + bb[3]);
    *(float4*)(cp + 4) = f4(acc[i][4] + bb[4], acc[i][5] + bb[5],
                            acc[i][6] + bb[6], acc[i][7] + bb[7]);
  }
}

// ------------------------------ phase A ------------------------------------
// Per (b,h,chunk): KVc[r][c] = sum_t kf_t[r] * v_t[c]; kstc[r] = sum_t kf_t[r]
__global__ __launch_bounds__(256) void phaseA(
    const float* __restrict__ klin, const float* __restrict__ vbuf,
    float* __restrict__ KVc, float* __restrict__ kstc) {
  __shared__ float kf[32 * DFEAT];   // 34944 B
  __shared__ float vv[32][64];       // 8192 B
  __shared__ float ks[32][16];       // 2048 B
  const int tid = threadIdx.x;
  const int bh = blockIdx.x >> 4, ck = blockIdx.x & 15;
  const int b = bh >> 4, hh = bh & 15;
  const int rq = tid >> 2;           // 0..63  -> rows rq*5..rq*5+4
  const int cg = (tid & 3) * 16;     // 16-col group
  float acc[5][16] = {};
  float kst0 = 0.f, kst1 = 0.f;
  for (int sg = 0; sg < 4; ++sg) {
    const int tbase = ck * CHUNK + sg * 32;
    if (tid < 128) {
      int tt = tid >> 2, i4 = (tid & 3) * 4;
      const float* kp = klin + ((size_t)(b * LL + tbase + tt)) * 256 + hh * 16 + i4;
      *(float4*)&ks[tt][i4] = *(const float4*)kp;
    }
#pragma unroll
    for (int p = 0; p < 2; p++) {
      int g = tid + p * 256;
      int tt = g >> 4, c4 = (g & 15) * 4;
      const float* vp = vbuf + ((size_t)(b * LL + tbase + tt)) * DD + hh * 64 + c4;
      *(float4*)&vv[tt][c4] = *(const float4*)vp;
    }
    __syncthreads();
    for (int e = tid; e < 32 * DFEAT; e += 256) {
      int tt = e / DFEAT, r = e - tt * DFEAT;
      float val;
      if (r == 0) val = 1.0f;
      else if (r < 17) val = ks[tt][r - 1] * 0.5f;
      else {
        int rr = r - 17;
        val = ks[tt][rr >> 4] * ks[tt][rr & 15] * 0.17677669529663687f;
      }
      kf[e] = val;
    }
    __syncthreads();
    for (int tt = 0; tt < 32; ++tt) {
      float4 v0 = *(const float4*)&vv[tt][cg];
      float4 v1 = *(const float4*)&vv[tt][cg + 4];
      float4 v2 = *(const float4*)&vv[tt][cg + 8];
      float4 v3 = *(const float4*)&vv[tt][cg + 12];
      float vr[16] = {v0.x, v0.y, v0.z, v0.w, v1.x, v1.y, v1.z, v1.w,
                      v2.x, v2.y, v2.z, v2.w, v3.x, v3.y, v3.z, v3.w};
#pragma unroll
      for (int ri = 0; ri < 5; ri++) {
        int r = rq * 5 + ri;
        float kv = kf[tt * DFEAT + (r < DFEAT ? r : 0)];
#pragma unroll
        for (int c = 0; c < 16; c++) acc[ri][c] = fmaf(kv, vr[c], acc[ri][c]);
      }
    }
    {
      float s0 = 0.f, s1 = 0.f;
      for (int tt = 0; tt < 32; ++tt) {
        s0 += kf[tt * DFEAT + tid];
        if (tid < 17) s1 += kf[tt * DFEAT + 256 + tid];
      }
      kst0 += s0;
      if (tid < 17) kst1 += s1;
    }
    __syncthreads();
  }
  const size_t cb = ((size_t)bh * NC + ck) * (DFEAT * 64);
#pragma unroll
  for (int ri = 0; ri < 5; ri++) {
    int r = rq * 5 + ri;
    if (r < DFEAT) {
      float* p = KVc + cb + (size_t)r * 64 + cg;
      *(float4*)(p + 0)  = f4(acc[ri][0], acc[ri][1], acc[ri][2], acc[ri][3]);
      *(float4*)(p + 4)  = f4(acc[ri][4], acc[ri][5], acc[ri][6], acc[ri][7]);
      *(float4*)(p + 8)  = f4(acc[ri][8], acc[ri][9], acc[ri][10], acc[ri][11]);
      *(float4*)(p + 12) = f4(acc[ri][12], acc[ri][13], acc[ri][14], acc[ri][15]);
    }
  }
  const size_t kb = ((size_t)bh * NC + ck) * DFEAT;
  kstc[kb + tid] = kst0;
  if (tid < 17) kstc[kb + 256 + tid] = kst1;
}

// ------------------------------ phase B ------------------------------------
// Exclusive prefix over chunks (in place), starting from input state; final
// inclusive sum -> kv_new / k_new outputs.
__global__ __launch_bounds__(256) void phaseB(
    float* __restrict__ KVc, float* __restrict__ kstc,
    const float* __restrict__ kv0, const float* __restrict__ kst0,
    float* __restrict__ kv_out, float* __restrict__ kst_out) {
  const int bh = blockIdx.x, tid = threadIdx.x;
  for (int e = tid; e < DFEAT * 64; e += 256) {
    float acc = kv0[(size_t)bh * (DFEAT * 64) + e];
    for (int ck = 0; ck < NC; ++ck) {
      size_t idx = ((size_t)bh * NC + ck) * (DFEAT * 64) + e;
      float t = KVc[idx]; KVc[idx] = acc; acc += t;
    }
    kv_out[(size_t)bh * (DFEAT * 64) + e] = acc;
  }
  for (int e = tid; e < DFEAT; e += 256) {
    float acc = kst0[bh * DFEAT + e];
    for (int ck = 0; ck < NC; ++ck) {
      size_t idx = ((size_t)bh * NC + ck) * DFEAT + e;
      float t = kstc[idx]; kstc[idx] = acc; acc += t;
    }
    kst_out[bh * DFEAT + e] = acc;
  }
}

// ------------------------------ phase C ------------------------------------
__global__ __launch_bounds__(256) void phaseC(
    const float* __restrict__ qlin, const float* __restrict__ klin,
    const float* __restrict__ vbuf, const float* __restrict__ KVc,
    const float* __restrict__ kstc, float* __restrict__ outs) {
  __shared__ float q_s[128][17];     // 8704
  __shared__ float k_s[64][17];      // 4352
  __shared__ float v_s[64][64];      // 16384
  __shared__ float S[64][132];       // 33792  (S[s][t])
  __shared__ float kst_s[DFEAT];     // 1092
  __shared__ float den_s[128];       // 512      total 64836 B
  const int tid = threadIdx.x;
  const int bh = blockIdx.x >> 4, ck = blockIdx.x & 15;
  const int b = bh >> 4, hh = bh & 15;
  const int t0 = ck * CHUNK;
  {
    int r = tid >> 1, i8 = (tid & 1) * 8;
    const float* qp = qlin + ((size_t)(b * LL + t0 + r)) * 256 + hh * 16 + i8;
    float4 a = *(const float4*)qp;
    float4 c = *(const float4*)(qp + 4);
    q_s[r][i8 + 0] = a.x; q_s[r][i8 + 1] = a.y; q_s[r][i8 + 2] = a.z; q_s[r][i8 + 3] = a.w;
    q_s[r][i8 + 4] = c.x; q_s[r][i8 + 5] = c.y; q_s[r][i8 + 6] = c.z; q_s[r][i8 + 7] = c.w;
  }
  for (int e = tid; e < DFEAT; e += 256)
    kst_s[e] = kstc[((size_t)bh * NC + ck) * DFEAT + e];
  if (tid < 128) den_s[tid] = 1e-6f;
  __syncthreads();
  const int tx = tid & 7;        // col group: c = tx*8..tx*8+7
  const int ty = tid >> 3;       // 0..31 -> t rows ty*4..ty*4+3
  const int t4 = ty * 4;
  float qr[4][16];
#pragma unroll
  for (int ii = 0; ii < 4; ii++)
#pragma unroll
    for (int i = 0; i < 16; i++) qr[ii][i] = q_s[t4 + ii][i];
  float num[4][8] = {};
  float den[4] = {};
  const float* kvb = KVc + ((size_t)bh * NC + ck) * (DFEAT * 64) + tx * 8;
  {  // r = 0 (constant feature)
    float4 a = *(const float4*)kvb;
    float4 c = *(const float4*)(kvb + 4);
    float k0v = kst_s[0];
#pragma unroll
    for (int ii = 0; ii < 4; ii++) {
      num[ii][0] += a.x; num[ii][1] += a.y; num[ii][2] += a.z; num[ii][3] += a.w;
      num[ii][4] += c.x; num[ii][5] += c.y; num[ii][6] += c.z; num[ii][7] += c.w;
      den[ii] += k0v;
    }
  }
  for (int i = 0; i < 16; i++) {  // linear features
    const float* p = kvb + (1 + i) * 64;
    float4 a = *(const float4*)p;
    float4 c = *(const float4*)(p + 4);
    float ksv = kst_s[1 + i];
#pragma unroll
    for (int ii = 0; ii < 4; ii++) {
      float coef = q_s[t4 + ii][i] * 0.5f;
      num[ii][0] = fmaf(coef, a.x, num[ii][0]); num[ii][1] = fmaf(coef, a.y, num[ii][1]);
      num[ii][2] = fmaf(coef, a.z, num[ii][2]); num[ii][3] = fmaf(coef, a.w, num[ii][3]);
      num[ii][4] = fmaf(coef, c.x, num[ii][4]); num[ii][5] = fmaf(coef, c.y, num[ii][5]);
      num[ii][6] = fmaf(coef, c.z, num[ii][6]); num[ii][7] = fmaf(coef, c.w, num[ii][7]);
      den[ii] = fmaf(coef, ksv, den[ii]);
    }
  }
  for (int i = 0; i < 16; i++) {  // quadratic features: r = 17 + i*16 + j
    float qi[4];
#pragma unroll
    for (int ii = 0; ii < 4; ii++) qi[ii] = q_s[t4 + ii][i] * 0.17677669529663687f;
    const float* pb = kvb + (17 + i * 16) * 64;
#pragma unroll
    for (int j = 0; j < 16; j++) {
      float4 a = *(const float4*)(pb + j * 64);
      float4 c = *(const float4*)(pb + j * 64 + 4);
      float ksv = kst_s[17 + i * 16 + j];
#pragma unroll
      for (int ii = 0; ii < 4; ii++) {
        float coef = qi[ii] * qr[ii][j];
        num[ii][0] = fmaf(coef, a.x, num[ii][0]); num[ii][1] = fmaf(coef, a.y, num[ii][1]);
        num[ii][2] = fmaf(coef, a.z, num[ii][2]); num[ii][3] = fmaf(coef, a.w, num[ii][3]);
        num[ii][4] = fmaf(coef, c.x, num[ii][4]); num[ii][5] = fmaf(coef, c.y, num[ii][5]);
        num[ii][6] = fmaf(coef, c.z, num[ii][6]); num[ii][7] = fmaf(coef, c.w, num[ii][7]);
        den[ii] = fmaf(coef, ksv, den[ii]);
      }
    }
  }
  if (tx == 0) {
#pragma unroll
    for (int ii = 0; ii < 4; ii++) den_s[t4 + ii] += den[ii];
  }
  __syncthreads();
  for (int st = 0; st < 2; ++st) {
    {
      int s = tid >> 2, i4 = (tid & 3) * 4;
      const float* kp = klin + ((size_t)(b * LL + t0 + st * 64 + s)) * 256 + hh * 16 + i4;
      float4 a = *(const float4*)kp;
      k_s[s][i4 + 0] = a.x; k_s[s][i4 + 1] = a.y; k_s[s][i4 + 2] = a.z; k_s[s][i4 + 3] = a.w;
    }
#pragma unroll
    for (int p = 0; p < 4; p++) {
      int g = tid + p * 256;
      int s = g >> 4, c4 = (g & 15) * 4;
      const float* vp = vbuf + ((size_t)(b * LL + t0 + st * 64 + s)) * DD + hh * 64 + c4;
      *(float4*)&v_s[s][c4] = *(const float4*)vp;
    }
    __syncthreads();
    {  // S = masked(1 + u/4 + u^2/32), u = q.k, stored S[s][t]
      float u[4][8] = {};
#pragma unroll
      for (int i = 0; i < 16; i++) {
        float bv[8];
#pragma unroll
        for (int jj = 0; jj < 8; jj++) bv[jj] = k_s[tx * 8 + jj][i];
#pragma unroll
        for (int ii = 0; ii < 4; ii++)
#pragma unroll
          for (int jj = 0; jj < 8; jj++)
            u[ii][jj] = fmaf(qr[ii][i], bv[jj], u[ii][jj]);
      }
      float rs[4] = {};
#pragma unroll
      for (int ii = 0; ii < 4; ii++) {
        int t = t4 + ii;
#pragma unroll
        for (int jj = 0; jj < 8; jj++) {
          int s_in = st * 64 + tx * 8 + jj;
          float uu = u[ii][jj];
          float sv = (s_in <= t) ? fmaf(uu, fmaf(uu, 0.03125f, 0.25f), 1.0f) : 0.0f;
          u[ii][jj] = sv;
          rs[ii] += sv;
        }
      }
#pragma unroll
      for (int jj = 0; jj < 8; jj++)
        *(float4*)&S[tx * 8 + jj][t4] = f4(u[0][jj], u[1][jj], u[2][jj], u[3][jj]);
#pragma unroll
      for (int ii = 0; ii < 4; ii++) {
        rs[ii] += __shfl_xor(rs[ii], 1);
        rs[ii] += __shfl_xor(rs[ii], 2);
        rs[ii] += __shfl_xor(rs[ii], 4);
      }
      if (tx == 0) {
#pragma unroll
        for (int ii = 0; ii < 4; ii++) den_s[t4 + ii] += rs[ii];
      }
    }
    __syncthreads();
#pragma unroll 4
    for (int ss = 0; ss < 64; ++ss) {  // num += S @ V
      float4 sv = *(const float4*)&S[ss][t4];
      float4 va = *(const float4*)&v_s[ss][tx * 8];
      float4 vb = *(const float4*)&v_s[ss][tx * 8 + 4];
      float vv8[8] = {va.x, va.y, va.z, va.w, vb.x, vb.y, vb.z, vb.w};
      float sr[4] = {sv.x, sv.y, sv.z, sv.w};
#pragma unroll
      for (int ii = 0; ii < 4; ii++)
#pragma unroll
        for (int jj = 0; jj < 8; jj++)
          num[ii][jj] = fmaf(sr[ii], vv8[jj], num[ii][jj]);
    }
    __syncthreads();
  }
#pragma unroll
  for (int ii = 0; ii < 4; ii++) {
    int t = t4 + ii;
    float inv = 1.0f / den_s[t];
    float* op = outs + ((size_t)(b * LL + t0 + t)) * DD + hh * 64 + tx * 8;
    *(float4*)op = f4(num[ii][0] * inv, num[ii][1] * inv, num[ii][2] * inv, num[ii][3] * inv);
    *(float4*)(op + 4) = f4(num[ii][4] * inv, num[ii][5] * inv, num[ii][6] * inv, num[ii][7] * inv);
  }
}

// --------------------------- last-row k2/v2 --------------------------------
__global__ __launch_bounds__(256) void lastrow_qkv(
    const float* __restrict__ x1,
    const float* __restrict__ Wk, const float* __restrict__ bk,
    const float* __restrict__ Wv, const float* __restrict__ bv,
    float* __restrict__ klast, float* __restrict__ vlast) {
  int gid = blockIdx.x * 256 + threadIdx.x;  // 8192 threads
  int which = gid >> 12;
  int b = (gid >> 10) & 3;
  int n = gid & 1023;
  const float* W = which ? Wv : Wk;
  const float* xr = x1 + ((size_t)(b * LL + LL - 1)) * DD;
  float s = 0.f;
  for (int k = 0; k < 1024; k++) s = fmaf(xr[k], W[(size_t)k * 1024 + n], s);
  s += which ? bv[n] : bk[n];
  (which ? vlast : klast)[b * 1024 + n] = s;
}

// --------------------------- window attention ------------------------------
__global__ __launch_bounds__(256) void window_attn(
    const float* __restrict__ q2, const float* __restrict__ klast,
    const float* __restrict__ vlast, const float* __restrict__ kbuf,
    const float* __restrict__ vbufw, float* __restrict__ win) {
  __shared__ float ukT[64][68];  // [d][wi]
  __shared__ float uvs[64][68];  // [wi][c]
  __shared__ float S[64][68];    // q tile -> scores -> attn
  const int tid = threadIdx.x;
  const int bh = blockIdx.x >> 5, tile = blockIdx.x & 31;
  const int b = bh >> 4, hh = bh & 15;
#pragma unroll
  for (int p = 0; p < 4; p++) {
    int g = tid + p * 256;
    int wi = g >> 4, d4 = (g & 15) * 4;
    const float* kp = (wi < 63) ? (kbuf + ((size_t)hh * 64 + wi + 1) * 64 + d4)
                                : (klast + (size_t)b * 1024 + hh * 64 + d4);
    float4 kk = *(const float4*)kp;
    ukT[d4 + 0][wi] = kk.x; ukT[d4 + 1][wi] = kk.y;
    ukT[d4 + 2][wi] = kk.z; ukT[d4 + 3][wi] = kk.w;
    const float* vp = (wi < 63) ? (vbufw + ((size_t)hh * 64 + wi + 1) * 64 + d4)
                                : (vlast + (size_t)b * 1024 + hh * 64 + d4);
    *(float4*)&uvs[wi][d4] = *(const float4*)vp;
    const float* qp = q2 + ((size_t)(b * LL + tile * 64 + wi)) * DD + hh * 64 + d4;
    *(float4*)&S[wi][d4] = *(const float4*)qp;
  }
  __syncthreads();
  const int tx = tid & 7, ty = tid >> 3;
  const int t2 = ty * 2;
  float a[2][8] = {};
  for (int d = 0; d < 64; ++d) {
    float q0 = S[t2][d], q1 = S[t2 + 1][d];
    float4 u0 = *(const float4*)&ukT[d][tx * 8];
    float4 u1 = *(const float4*)&ukT[d][tx * 8 + 4];
    float uk8[8] = {u0.x, u0.y, u0.z, u0.w, u1.x, u1.y, u1.z, u1.w};
#pragma unroll
    for (int j = 0; j < 8; j++) {
      a[0][j] = fmaf(q0, uk8[j], a[0][j]);
      a[1][j] = fmaf(q1, uk8[j], a[1][j]);
    }
  }
  __syncthreads();
#pragma unroll
  for (int ii = 0; ii < 2; ii++) {
    *(float4*)&S[t2 + ii][tx * 8] =
        f4(a[ii][0] * 0.125f, a[ii][1] * 0.125f, a[ii][2] * 0.125f, a[ii][3] * 0.125f);
    *(float4*)&S[t2 + ii][tx * 8 + 4] =
        f4(a[ii][4] * 0.125f, a[ii][5] * 0.125f, a[ii][6] * 0.125f, a[ii][7] * 0.125f);
  }
  __syncthreads();
  if (tid < 64) {
    float v[64];
#pragma unroll
    for (int i = 0; i < 16; i++) *(float4*)&v[i * 4] = *(const float4*)&S[tid][i * 4];
    float m = v[0];
#pragma unroll
    for (int i = 1; i < 64; i++) m = fmaxf(m, v[i]);
    float l = 0.f;
#pragma unroll
    for (int i = 0; i < 64; i++) { v[i] = expf(v[i] - m); l += v[i]; }
    float inv = 1.0f / l;
#pragma unroll
    for (int i = 0; i < 16; i++)
      *(float4*)&S[tid][i * 4] =
          f4(v[i * 4] * inv, v[i * 4 + 1] * inv, v[i * 4 + 2] * inv, v[i * 4 + 3] * inv);
  }
  __syncthreads();
  float o[2][8] = {};
  for (int w = 0; w < 64; ++w) {
    float a0 = S[t2][w], a1 = S[t2 + 1][w];
    float4 x0 = *(const float4*)&uvs[w][tx * 8];
    float4 x1v = *(const float4*)&uvs[w][tx * 8 + 4];
    float uv8[8] = {x0.x, x0.y, x0.z, x0.w, x1v.x, x1v.y, x1v.z, x1v.w};
#pragma unroll
    for (int j = 0; j < 8; j++) {
      o[0][j] = fmaf(a0, uv8[j], o[0][j]);
      o[1][j] = fmaf(a1, uv8[j], o[1][j]);
    }
  }
#pragma unroll
  for (int ii = 0; ii < 2; ii++) {
    float* wp = win + ((size_t)(b * LL + tile * 64 + t2 + ii)) * DD + hh * 64 + tx * 8;
    *(float4*)wp = f4(o[ii][0], o[ii][1], o[ii][2], o[ii][3]);
    *(float4*)(wp + 4) = f4(o[ii][4], o[ii][5], o[ii][6], o[ii][7]);
  }
}

// ------------------------------ LayerNorm ----------------------------------
__global__ __launch_bounds__(256) void ln_add(
    const float* __restrict__ A, const float* __restrict__ Bm,
    const float* __restrict__ gamma, const float* __restrict__ beta,
    float* __restrict__ out) {
  const int row = blockIdx.x, tid = threadIdx.x;
  float4 va = ((const float4*)(A + (size_t)row * DD))[tid];
  float4 vb = ((const float4*)(Bm + (size_t)row * DD))[tid];
  float4 s4 = f4(va.x + vb.x, va.y + vb.y, va.z + vb.z, va.w + vb.w);
  float s = s4.x + s4.y + s4.z + s4.w;
  float ss = s4.x * s4.x + s4.y * s4.y + s4.z * s4.z + s4.w * s4.w;
  for (int o = 32; o; o >>= 1) { s += __shfl_xor(s, o); ss += __shfl_xor(ss, o); }
  __shared__ float red[8];
  int wid = tid >> 6;
  if ((tid & 63) == 0) { red[wid * 2] = s; red[wid * 2 + 1] = ss; }
  __syncthreads();
  float tot = red[0] + red[2] + red[4] + red[6];
  float tots = red[1] + red[3] + red[5] + red[7];
  float mu = tot * (1.0f / 1024.0f);
  float var = tots * (1.0f / 1024.0f) - mu * mu;
  float rstd = rsqrtf(var + 1e-5f);
  float4 g = ((const float4*)gamma)[tid];
  float4 be = ((const float4*)beta)[tid];
  float4 o = f4((s4.x - mu) * rstd * g.x + be.x, (s4.y - mu) * rstd * g.y + be.y,
                (s4.z - mu) * rstd * g.z + be.z, (s4.w - mu) * rstd * g.w + be.w);
  ((float4*)(out + (size_t)row * DD))[tid] = o;
}

// ------------------------------ launch -------------------------------------
extern "C" void kernel_launch(void* const* d_in, const int* in_sizes, int n_in,
                              void* d_out, int out_size, void* d_ws, size_t ws_size,
                              hipStream_t stream) {
  (void)in_sizes; (void)n_in; (void)out_size; (void)ws_size;
  const float* x      = (const float*)d_in[0];
  const float* kv0    = (const float*)d_in[1];
  const float* kst0   = (const float*)d_in[2];
  const float* kbuf   = (const float*)d_in[3];
  const float* vbufw  = (const float*)d_in[4];
  const float* Wq_lin = (const float*)d_in[5];
  const float* bq_lin = (const float*)d_in[6];
  const float* Wk_lin = (const float*)d_in[7];
  const float* bk_lin = (const float*)d_in[8];
  const float* Wv_lin = (const float*)d_in[9];
  const float* bv_lin = (const float*)d_in[10];
  const float* Wo_lin = (const float*)d_in[11];
  const float* bo_lin = (const float*)d_in[12];
  const float* Wq     = (const float*)d_in[13];
  const float* bq     = (const float*)d_in[14];
  const float* Wk     = (const float*)d_in[15];
  const float* bk     = (const float*)d_in[16];
  const float* Wv     = (const float*)d_in[17];
  const float* bv     = (const float*)d_in[18];
  const float* Wo     = (const float*)d_in[19];
  const float* bo     = (const float*)d_in[20];
  const float* gamma  = (const float*)d_in[21];
  const float* beta   = (const float*)d_in[22];

  float* out = (float*)d_out;
  // Output tuple: out (4,2048,1024)=8388608 | kv_new (4,16,273,64)=1118208 |
  // k_new (4,16,273)=17472.  (Round-1 fix: kst_out offset.)
  float* kv_out  = out + 8388608;
  float* kst_out = out + 8388608 + 1118208;  // = 9506816

  float* ws = (float*)d_ws;
  const size_t MF = 1024 * 1024;
  float* qlin  = ws + 0;                  // [0, 2M)
  float* klin  = ws + 2 * MF;             // [2M, 4M)
  float* v     = ws + 4 * MF;             // [4M, 12M)
  float* KVc   = ws + 12 * MF;            // [12M, ~29.06M)
  float* kstc  = ws + 12 * MF + 17891328; // 279552 floats
  float* outsb = ws + 31 * MF;            // [31M, 39M)
  float* tmp   = ws + 20 * MF;            // [20M, 28M)  (KVc dead)
  float* x1    = ws + 12 * MF;            // [12M, 20M)  (KVc dead)
  float* q2    = ws + 31 * MF;            // [31M, 39M)  (outs dead)
  float* klast = ws + 28 * MF;            // 4096 floats
  float* vlast = ws + 28 * MF + 4096;
  float* winb  = ws + 0;                  // [0, 8M)     (qlin/klin/v dead)
  float* tmp2  = ws + 31 * MF;            // [31M, 39M)  (q2 dead)

  dim3 blk(256);
  gemm_bias<<<dim3(64, 2), blk, 0, stream>>>(x, Wq_lin, bq_lin, qlin, 8192, 256, 1024);
  gemm_bias<<<dim3(64, 2), blk, 0, stream>>>(x, Wk_lin, bk_lin, klin, 8192, 256, 1024);
  gemm_bias<<<dim3(64, 8), blk, 0, stream>>>(x, Wv_lin, bv_lin, v, 8192, 1024, 1024);
  phaseA<<<1024, blk, 0, stream>>>(klin, v, KVc, kstc);
  phaseB<<<64, blk, 0, stream>>>(KVc, kstc, kv0, kst0, kv_out, kst_out);
  phaseC<<<1024, blk, 0, stream>>>(qlin, klin, v, KVc, kstc, outsb);
  gemm_bias<<<dim3(64, 8), blk, 0, stream>>>(outsb, Wo_lin, bo_lin, tmp, 8192, 1024, 1024);
  ln_add<<<8192, blk, 0, stream>>>(x, tmp, gamma, beta, x1);
  gemm_bias<<<dim3(64, 8), blk, 0, stream>>>(x1, Wq, bq, q2, 8192, 1024, 1024);
  lastrow_qkv<<<32, blk, 0, stream>>>(x1, Wk, bk, Wv, bv, klast, vlast);
  window_attn<<<2048, blk, 0, stream>>>(q2, klast, vlast, kbuf, vbufw, winb);
  gemm_bias<<<dim3(64, 8), blk, 0, stream>>>(winb, Wo, bo, tmp2, 8192, 1024, 1024);
  ln_add<<<8192, blk, 0, stream>>>(x1, tmp2, gamma, beta, out);
}

// Round 3
// 803.961 us; speedup vs baseline: 2.1834x; 2.1834x over previous
//
#include <hip/hip_runtime.h>
#include <math.h>

// ---------------------------------------------------------------------------
// BasedBlock: B=4 L=2048 d=1024 h=16 f=16 hd=64 w=64, D=1+f+f*f=273
// Round 2: all six big GEMMs -> bf16 MFMA (16x16x32), m97-style:
//   128x128 tile, 4 waves x (4x4) MFMA tiles, BK=64,
//   global_load_lds width=16 staging, XOR-swizzled LDS (conflict-free b128).
// Weights cast+transposed to [N][K] bf16 in-call; chained A-inputs written
// bf16 by producers (phaseC / ln_add / window_attn). fp32 accum + bias.
// ---------------------------------------------------------------------------

#define LL 2048
#define DD 1024
#define DFEAT 273
#define NC 16
#define CHUNK 128

typedef __attribute__((ext_vector_type(8))) short short8;
typedef __attribute__((ext_vector_type(4))) float f32x4;

__device__ __forceinline__ float4 f4(float a, float b, float c, float d) {
  float4 r; r.x = a; r.y = b; r.z = c; r.w = d; return r;
}

__device__ __forceinline__ unsigned short f2bf(float f) {
  union { float f; unsigned u; } v; v.f = f;
  unsigned r = v.u + 0x7fffu + ((v.u >> 16) & 1u);
  return (unsigned short)(r >> 16);
}

// --------------------------- cast kernels ----------------------------------
__global__ __launch_bounds__(256) void cast_bf16(
    const float* __restrict__ in, unsigned short* __restrict__ o, int n4) {
  int i = blockIdx.x * 256 + threadIdx.x;
  if (i < n4) {
    float4 v = ((const float4*)in)[i];
    ushort4 r;
    r.x = f2bf(v.x); r.y = f2bf(v.y); r.z = f2bf(v.z); r.w = f2bf(v.w);
    ((ushort4*)o)[i] = r;
  }
}

// W[K][N] fp32 -> Wt[N][K] bf16
__global__ __launch_bounds__(256) void castT(
    const float* __restrict__ W, unsigned short* __restrict__ Wt, int K, int N) {
  __shared__ float t[64][65];
  int k0 = blockIdx.x * 64, n0 = blockIdx.y * 64;
  int tid = threadIdx.x;
#pragma unroll
  for (int p = 0; p < 16; p++) {
    int idx = p * 256 + tid;
    int r = idx >> 6, c = idx & 63;
    t[r][c] = W[(size_t)(k0 + r) * N + n0 + c];
  }
  __syncthreads();
#pragma unroll
  for (int p = 0; p < 16; p++) {
    int idx = p * 256 + tid;
    int rn = idx >> 6, ck = idx & 63;
    Wt[(size_t)(n0 + rn) * K + k0 + ck] = f2bf(t[ck][rn]);
  }
}

// --------------------------- MFMA GEMM -------------------------------------
// C[M,N] = A[M,K](bf16) @ Bt[N,K](bf16)^T + bias. M%128==0, N%128==0, K%64==0.
__global__ __launch_bounds__(256) void gemm_mfma(
    const unsigned short* __restrict__ A, const unsigned short* __restrict__ Bt,
    const float* __restrict__ bias, float* __restrict__ C,
    int M, int N, int K) {
  __shared__ unsigned short As[128 * 64];  // 16 KB, row r: granule g holds k-group g^(r&7)
  __shared__ unsigned short Bs[128 * 64];  // 16 KB
  const int tid = threadIdx.x;
  const int lane = tid & 63, w = tid >> 6;
  const int row0 = blockIdx.x * 128, col0 = blockIdx.y * 128;
  const int wm0 = (w & 1) * 64, wn0 = (w >> 1) * 64;
  const int lr = lane >> 3;            // 0..7
  const int gc = (lane & 7) ^ lr;      // swizzled k-granule to fetch
  const unsigned short* aP = A + (size_t)(row0 + w * 32 + lr) * K + gc * 8;
  const unsigned short* bP = Bt + (size_t)(col0 + w * 32 + lr) * K + gc * 8;
  unsigned short* asW = As + w * 2048;
  unsigned short* bsW = Bs + w * 2048;
  const int m15 = lane & 15, quad = lane >> 4;
  f32x4 acc[4][4] = {};
  for (int k0 = 0; k0 < K; k0 += 64) {
#pragma unroll
    for (int i = 0; i < 4; i++) {
      __builtin_amdgcn_global_load_lds(
          (const __attribute__((address_space(1))) unsigned int*)(const void*)(aP + (size_t)(i * 8) * K + k0),
          (__attribute__((address_space(3))) unsigned int*)(void*)(asW + i * 512), 16, 0, 0);
      __builtin_amdgcn_global_load_lds(
          (const __attribute__((address_space(1))) unsigned int*)(const void*)(bP + (size_t)(i * 8) * K + k0),
          (__attribute__((address_space(3))) unsigned int*)(void*)(bsW + i * 512), 16, 0, 0);
    }
    __syncthreads();
#pragma unroll
    for (int ks = 0; ks < 2; ks++) {
      short8 aF[4], bF[4];
#pragma unroll
      for (int mi = 0; mi < 4; mi++) {
        int r = wm0 + mi * 16 + m15;
        int g = (ks * 4 + quad) ^ (r & 7);
        aF[mi] = *(const short8*)(As + r * 64 + g * 8);
      }
#pragma unroll
      for (int ni = 0; ni < 4; ni++) {
        int r = wn0 + ni * 16 + m15;
        int g = (ks * 4 + quad) ^ (r & 7);
        bF[ni] = *(const short8*)(Bs + r * 64 + g * 8);
      }
#pragma unroll
      for (int mi = 0; mi < 4; mi++)
#pragma unroll
        for (int ni = 0; ni < 4; ni++)
          acc[mi][ni] = __builtin_amdgcn_mfma_f32_16x16x32_bf16(
              aF[mi], bF[ni], acc[mi][ni], 0, 0, 0);
    }
    __syncthreads();
  }
#pragma unroll
  for (int mi = 0; mi < 4; mi++)
#pragma unroll
    for (int ni = 0; ni < 4; ni++) {
      int col = col0 + wn0 + ni * 16 + m15;
      float bb = bias[col];
#pragma unroll
      for (int r = 0; r < 4; r++) {
        int row = row0 + wm0 + mi * 16 + quad * 4 + r;
        C[(size_t)row * N + col] = acc[mi][ni][r] + bb;
      }
    }
}

// ------------------------------ phase A ------------------------------------
__global__ __launch_bounds__(256) void phaseA(
    const float* __restrict__ klin, const float* __restrict__ vbuf,
    float* __restrict__ KVc, float* __restrict__ kstc) {
  __shared__ float kf[32 * DFEAT];
  __shared__ float vv[32][64];
  __shared__ float ks[32][16];
  const int tid = threadIdx.x;
  const int bh = blockIdx.x >> 4, ck = blockIdx.x & 15;
  const int b = bh >> 4, hh = bh & 15;
  const int rq = tid >> 2;
  const int cg = (tid & 3) * 16;
  float acc[5][16] = {};
  float kst0 = 0.f, kst1 = 0.f;
  for (int sg = 0; sg < 4; ++sg) {
    const int tbase = ck * CHUNK + sg * 32;
    if (tid < 128) {
      int tt = tid >> 2, i4 = (tid & 3) * 4;
      const float* kp = klin + ((size_t)(b * LL + tbase + tt)) * 256 + hh * 16 + i4;
      *(float4*)&ks[tt][i4] = *(const float4*)kp;
    }
#pragma unroll
    for (int p = 0; p < 2; p++) {
      int g = tid + p * 256;
      int tt = g >> 4, c4 = (g & 15) * 4;
      const float* vp = vbuf + ((size_t)(b * LL + tbase + tt)) * DD + hh * 64 + c4;
      *(float4*)&vv[tt][c4] = *(const float4*)vp;
    }
    __syncthreads();
    for (int e = tid; e < 32 * DFEAT; e += 256) {
      int tt = e / DFEAT, r = e - tt * DFEAT;
      float val;
      if (r == 0) val = 1.0f;
      else if (r < 17) val = ks[tt][r - 1] * 0.5f;
      else {
        int rr = r - 17;
        val = ks[tt][rr >> 4] * ks[tt][rr & 15] * 0.17677669529663687f;
      }
      kf[e] = val;
    }
    __syncthreads();
    for (int tt = 0; tt < 32; ++tt) {
      float4 v0 = *(const float4*)&vv[tt][cg];
      float4 v1 = *(const float4*)&vv[tt][cg + 4];
      float4 v2 = *(const float4*)&vv[tt][cg + 8];
      float4 v3 = *(const float4*)&vv[tt][cg + 12];
      float vr[16] = {v0.x, v0.y, v0.z, v0.w, v1.x, v1.y, v1.z, v1.w,
                      v2.x, v2.y, v2.z, v2.w, v3.x, v3.y, v3.z, v3.w};
#pragma unroll
      for (int ri = 0; ri < 5; ri++) {
        int r = rq * 5 + ri;
        float kv = kf[tt * DFEAT + (r < DFEAT ? r : 0)];
#pragma unroll
        for (int c = 0; c < 16; c++) acc[ri][c] = fmaf(kv, vr[c], acc[ri][c]);
      }
    }
    {
      float s0 = 0.f, s1 = 0.f;
      for (int tt = 0; tt < 32; ++tt) {
        s0 += kf[tt * DFEAT + tid];
        if (tid < 17) s1 += kf[tt * DFEAT + 256 + tid];
      }
      kst0 += s0;
      if (tid < 17) kst1 += s1;
    }
    __syncthreads();
  }
  const size_t cb = ((size_t)bh * NC + ck) * (DFEAT * 64);
#pragma unroll
  for (int ri = 0; ri < 5; ri++) {
    int r = rq * 5 + ri;
    if (r < DFEAT) {
      float* p = KVc + cb + (size_t)r * 64 + cg;
      *(float4*)(p + 0)  = f4(acc[ri][0], acc[ri][1], acc[ri][2], acc[ri][3]);
      *(float4*)(p + 4)  = f4(acc[ri][4], acc[ri][5], acc[ri][6], acc[ri][7]);
      *(float4*)(p + 8)  = f4(acc[ri][8], acc[ri][9], acc[ri][10], acc[ri][11]);
      *(float4*)(p + 12) = f4(acc[ri][12], acc[ri][13], acc[ri][14], acc[ri][15]);
    }
  }
  const size_t kb = ((size_t)bh * NC + ck) * DFEAT;
  kstc[kb + tid] = kst0;
  if (tid < 17) kstc[kb + 256 + tid] = kst1;
}

// ------------------------------ phase B ------------------------------------
__global__ __launch_bounds__(256) void phaseB(
    float* __restrict__ KVc, float* __restrict__ kstc,
    const float* __restrict__ kv0, const float* __restrict__ kst0,
    float* __restrict__ kv_out, float* __restrict__ kst_out) {
  const int bh = blockIdx.x, tid = threadIdx.x;
  for (int e = tid; e < DFEAT * 64; e += 256) {
    float acc = kv0[(size_t)bh * (DFEAT * 64) + e];
    for (int ck = 0; ck < NC; ++ck) {
      size_t idx = ((size_t)bh * NC + ck) * (DFEAT * 64) + e;
      float t = KVc[idx]; KVc[idx] = acc; acc += t;
    }
    kv_out[(size_t)bh * (DFEAT * 64) + e] = acc;
  }
  for (int e = tid; e < DFEAT; e += 256) {
    float acc = kst0[bh * DFEAT + e];
    for (int ck = 0; ck < NC; ++ck) {
      size_t idx = ((size_t)bh * NC + ck) * DFEAT + e;
      float t = kstc[idx]; kstc[idx] = acc; acc += t;
    }
    kst_out[bh * DFEAT + e] = acc;
  }
}

// ------------------------------ phase C ------------------------------------
__global__ __launch_bounds__(256) void phaseC(
    const float* __restrict__ qlin, const float* __restrict__ klin,
    const float* __restrict__ vbuf, const float* __restrict__ KVc,
    const float* __restrict__ kstc, unsigned short* __restrict__ outs) {
  __shared__ float q_s[128][17];
  __shared__ float k_s[64][17];
  __shared__ float v_s[64][64];
  __shared__ float S[64][132];
  __shared__ float kst_s[DFEAT];
  __shared__ float den_s[128];
  const int tid = threadIdx.x;
  const int bh = blockIdx.x >> 4, ck = blockIdx.x & 15;
  const int b = bh >> 4, hh = bh & 15;
  const int t0 = ck * CHUNK;
  {
    int r = tid >> 1, i8 = (tid & 1) * 8;
    const float* qp = qlin + ((size_t)(b * LL + t0 + r)) * 256 + hh * 16 + i8;
    float4 a = *(const float4*)qp;
    float4 c = *(const float4*)(qp + 4);
    q_s[r][i8 + 0] = a.x; q_s[r][i8 + 1] = a.y; q_s[r][i8 + 2] = a.z; q_s[r][i8 + 3] = a.w;
    q_s[r][i8 + 4] = c.x; q_s[r][i8 + 5] = c.y; q_s[r][i8 + 6] = c.z; q_s[r][i8 + 7] = c.w;
  }
  for (int e = tid; e < DFEAT; e += 256)
    kst_s[e] = kstc[((size_t)bh * NC + ck) * DFEAT + e];
  if (tid < 128) den_s[tid] = 1e-6f;
  __syncthreads();
  const int tx = tid & 7;
  const int ty = tid >> 3;
  const int t4 = ty * 4;
  float qr[4][16];
#pragma unroll
  for (int ii = 0; ii < 4; ii++)
#pragma unroll
    for (int i = 0; i < 16; i++) qr[ii][i] = q_s[t4 + ii][i];
  float num[4][8] = {};
  float den[4] = {};
  const float* kvb = KVc + ((size_t)bh * NC + ck) * (DFEAT * 64) + tx * 8;
  {
    float4 a = *(const float4*)kvb;
    float4 c = *(const float4*)(kvb + 4);
    float k0v = kst_s[0];
#pragma unroll
    for (int ii = 0; ii < 4; ii++) {
      num[ii][0] += a.x; num[ii][1] += a.y; num[ii][2] += a.z; num[ii][3] += a.w;
      num[ii][4] += c.x; num[ii][5] += c.y; num[ii][6] += c.z; num[ii][7] += c.w;
      den[ii] += k0v;
    }
  }
  for (int i = 0; i < 16; i++) {
    const float* p = kvb + (1 + i) * 64;
    float4 a = *(const float4*)p;
    float4 c = *(const float4*)(p + 4);
    float ksv = kst_s[1 + i];
#pragma unroll
    for (int ii = 0; ii < 4; ii++) {
      float coef = q_s[t4 + ii][i] * 0.5f;
      num[ii][0] = fmaf(coef, a.x, num[ii][0]); num[ii][1] = fmaf(coef, a.y, num[ii][1]);
      num[ii][2] = fmaf(coef, a.z, num[ii][2]); num[ii][3] = fmaf(coef, a.w, num[ii][3]);
      num[ii][4] = fmaf(coef, c.x, num[ii][4]); num[ii][5] = fmaf(coef, c.y, num[ii][5]);
      num[ii][6] = fmaf(coef, c.z, num[ii][6]); num[ii][7] = fmaf(coef, c.w, num[ii][7]);
      den[ii] = fmaf(coef, ksv, den[ii]);
    }
  }
  for (int i = 0; i < 16; i++) {
    float qi[4];
#pragma unroll
    for (int ii = 0; ii < 4; ii++) qi[ii] = q_s[t4 + ii][i] * 0.17677669529663687f;
    const float* pb = kvb + (17 + i * 16) * 64;
#pragma unroll
    for (int j = 0; j < 16; j++) {
      float4 a = *(const float4*)(pb + j * 64);
      float4 c = *(const float4*)(pb + j * 64 + 4);
      float ksv = kst_s[17 + i * 16 + j];
#pragma unroll
      for (int ii = 0; ii < 4; ii++) {
        float coef = qi[ii] * qr[ii][j];
        num[ii][0] = fmaf(coef, a.x, num[ii][0]); num[ii][1] = fmaf(coef, a.y, num[ii][1]);
        num[ii][2] = fmaf(coef, a.z, num[ii][2]); num[ii][3] = fmaf(coef, a.w, num[ii][3]);
        num[ii][4] = fmaf(coef, c.x, num[ii][4]); num[ii][5] = fmaf(coef, c.y, num[ii][5]);
        num[ii][6] = fmaf(coef, c.z, num[ii][6]); num[ii][7] = fmaf(coef, c.w, num[ii][7]);
        den[ii] = fmaf(coef, ksv, den[ii]);
      }
    }
  }
  if (tx == 0) {
#pragma unroll
    for (int ii = 0; ii < 4; ii++) den_s[t4 + ii] += den[ii];
  }
  __syncthreads();
  for (int st = 0; st < 2; ++st) {
    {
      int s = tid >> 2, i4 = (tid & 3) * 4;
      const float* kp = klin + ((size_t)(b * LL + t0 + st * 64 + s)) * 256 + hh * 16 + i4;
      float4 a = *(const float4*)kp;
      k_s[s][i4 + 0] = a.x; k_s[s][i4 + 1] = a.y; k_s[s][i4 + 2] = a.z; k_s[s][i4 + 3] = a.w;
    }
#pragma unroll
    for (int p = 0; p < 4; p++) {
      int g = tid + p * 256;
      int s = g >> 4, c4 = (g & 15) * 4;
      const float* vp = vbuf + ((size_t)(b * LL + t0 + st * 64 + s)) * DD + hh * 64 + c4;
      *(float4*)&v_s[s][c4] = *(const float4*)vp;
    }
    __syncthreads();
    {
      float u[4][8] = {};
#pragma unroll
      for (int i = 0; i < 16; i++) {
        float bv[8];
#pragma unroll
        for (int jj = 0; jj < 8; jj++) bv[jj] = k_s[tx * 8 + jj][i];
#pragma unroll
        for (int ii = 0; ii < 4; ii++)
#pragma unroll
          for (int jj = 0; jj < 8; jj++)
            u[ii][jj] = fmaf(qr[ii][i], bv[jj], u[ii][jj]);
      }
      float rs[4] = {};
#pragma unroll
      for (int ii = 0; ii < 4; ii++) {
        int t = t4 + ii;
#pragma unroll
        for (int jj = 0; jj < 8; jj++) {
          int s_in = st * 64 + tx * 8 + jj;
          float uu = u[ii][jj];
          float sv = (s_in <= t) ? fmaf(uu, fmaf(uu, 0.03125f, 0.25f), 1.0f) : 0.0f;
          u[ii][jj] = sv;
          rs[ii] += sv;
        }
      }
#pragma unroll
      for (int jj = 0; jj < 8; jj++)
        *(float4*)&S[tx * 8 + jj][t4] = f4(u[0][jj], u[1][jj], u[2][jj], u[3][jj]);
#pragma unroll
      for (int ii = 0; ii < 4; ii++) {
        rs[ii] += __shfl_xor(rs[ii], 1);
        rs[ii] += __shfl_xor(rs[ii], 2);
        rs[ii] += __shfl_xor(rs[ii], 4);
      }
      if (tx == 0) {
#pragma unroll
        for (int ii = 0; ii < 4; ii++) den_s[t4 + ii] += rs[ii];
      }
    }
    __syncthreads();
#pragma unroll 4
    for (int ss = 0; ss < 64; ++ss) {
      float4 sv = *(const float4*)&S[ss][t4];
      float4 va = *(const float4*)&v_s[ss][tx * 8];
      float4 vb = *(const float4*)&v_s[ss][tx * 8 + 4];
      float vv8[8] = {va.x, va.y, va.z, va.w, vb.x, vb.y, vb.z, vb.w};
      float sr[4] = {sv.x, sv.y, sv.z, sv.w};
#pragma unroll
      for (int ii = 0; ii < 4; ii++)
#pragma unroll
        for (int jj = 0; jj < 8; jj++)
          num[ii][jj] = fmaf(sr[ii], vv8[jj], num[ii][jj]);
    }
    __syncthreads();
  }
#pragma unroll
  for (int ii = 0; ii < 4; ii++) {
    int t = t4 + ii;
    float inv = 1.0f / den_s[t];
    unsigned short* op = outs + ((size_t)(b * LL + t0 + t)) * DD + hh * 64 + tx * 8;
    ushort4 r0, r1;
    r0.x = f2bf(num[ii][0] * inv); r0.y = f2bf(num[ii][1] * inv);
    r0.z = f2bf(num[ii][2] * inv); r0.w = f2bf(num[ii][3] * inv);
    r1.x = f2bf(num[ii][4] * inv); r1.y = f2bf(num[ii][5] * inv);
    r1.z = f2bf(num[ii][6] * inv); r1.w = f2bf(num[ii][7] * inv);
    *(ushort4*)op = r0;
    *(ushort4*)(op + 4) = r1;
  }
}

// --------------------------- last-row k2/v2 --------------------------------
__global__ __launch_bounds__(256) void lastrow_qkv(
    const float* __restrict__ x1,
    const float* __restrict__ Wk, const float* __restrict__ bk,
    const float* __restrict__ Wv, const float* __restrict__ bv,
    float* __restrict__ klast, float* __restrict__ vlast) {
  int gid = blockIdx.x * 256 + threadIdx.x;
  int which = gid >> 12;
  int b = (gid >> 10) & 3;
  int n = gid & 1023;
  const float* W = which ? Wv : Wk;
  const float* xr = x1 + ((size_t)(b * LL + LL - 1)) * DD;
  float s = 0.f;
  for (int k = 0; k < 1024; k++) s = fmaf(xr[k], W[(size_t)k * 1024 + n], s);
  s += which ? bv[n] : bk[n];
  (which ? vlast : klast)[b * 1024 + n] = s;
}

// --------------------------- window attention ------------------------------
__global__ __launch_bounds__(256) void window_attn(
    const float* __restrict__ q2, const float* __restrict__ klast,
    const float* __restrict__ vlast, const float* __restrict__ kbuf,
    const float* __restrict__ vbufw, unsigned short* __restrict__ win) {
  __shared__ float ukT[64][68];
  __shared__ float uvs[64][68];
  __shared__ float S[64][68];
  const int tid = threadIdx.x;
  const int bh = blockIdx.x >> 5, tile = blockIdx.x & 31;
  const int b = bh >> 4, hh = bh & 15;
#pragma unroll
  for (int p = 0; p < 4; p++) {
    int g = tid + p * 256;
    int wi = g >> 4, d4 = (g & 15) * 4;
    const float* kp = (wi < 63) ? (kbuf + ((size_t)hh * 64 + wi + 1) * 64 + d4)
                                : (klast + (size_t)b * 1024 + hh * 64 + d4);
    float4 kk = *(const float4*)kp;
    ukT[d4 + 0][wi] = kk.x; ukT[d4 + 1][wi] = kk.y;
    ukT[d4 + 2][wi] = kk.z; ukT[d4 + 3][wi] = kk.w;
    const float* vp = (wi < 63) ? (vbufw + ((size_t)hh * 64 + wi + 1) * 64 + d4)
                                : (vlast + (size_t)b * 1024 + hh * 64 + d4);
    *(float4*)&uvs[wi][d4] = *(const float4*)vp;
    const float* qp = q2 + ((size_t)(b * LL + tile * 64 + wi)) * DD + hh * 64 + d4;
    *(float4*)&S[wi][d4] = *(const float4*)qp;
  }
  __syncthreads();
  const int tx = tid & 7, ty = tid >> 3;
  const int t2 = ty * 2;
  float a[2][8] = {};
  for (int d = 0; d < 64; ++d) {
    float q0 = S[t2][d], q1 = S[t2 + 1][d];
    float4 u0 = *(const float4*)&ukT[d][tx * 8];
    float4 u1 = *(const float4*)&ukT[d][tx * 8 + 4];
    float uk8[8] = {u0.x, u0.y, u0.z, u0.w, u1.x, u1.y, u1.z, u1.w};
#pragma unroll
    for (int j = 0; j < 8; j++) {
      a[0][j] = fmaf(q0, uk8[j], a[0][j]);
      a[1][j] = fmaf(q1, uk8[j], a[1][j]);
    }
  }
  __syncthreads();
#pragma unroll
  for (int ii = 0; ii < 2; ii++) {
    *(float4*)&S[t2 + ii][tx * 8] =
        f4(a[ii][0] * 0.125f, a[ii][1] * 0.125f, a[ii][2] * 0.125f, a[ii][3] * 0.125f);
    *(float4*)&S[t2 + ii][tx * 8 + 4] =
        f4(a[ii][4] * 0.125f, a[ii][5] * 0.125f, a[ii][6] * 0.125f, a[ii][7] * 0.125f);
  }
  __syncthreads();
  if (tid < 64) {
    float v[64];
#pragma unroll
    for (int i = 0; i < 16; i++) *(float4*)&v[i * 4] = *(const float4*)&S[tid][i * 4];
    float m = v[0];
#pragma unroll
    for (int i = 1; i < 64; i++) m = fmaxf(m, v[i]);
    float l = 0.f;
#pragma unroll
    for (int i = 0; i < 64; i++) { v[i] = expf(v[i] - m); l += v[i]; }
    float inv = 1.0f / l;
#pragma unroll
    for (int i = 0; i < 16; i++)
      *(float4*)&S[tid][i * 4] =
          f4(v[i * 4] * inv, v[i * 4 + 1] * inv, v[i * 4 + 2] * inv, v[i * 4 + 3] * inv);
  }
  __syncthreads();
  float o[2][8] = {};
  for (int w = 0; w < 64; ++w) {
    float a0 = S[t2][w], a1 = S[t2 + 1][w];
    float4 x0 = *(const float4*)&uvs[w][tx * 8];
    float4 x1v = *(const float4*)&uvs[w][tx * 8 + 4];
    float uv8[8] = {x0.x, x0.y, x0.z, x0.w, x1v.x, x1v.y, x1v.z, x1v.w};
#pragma unroll
    for (int j = 0; j < 8; j++) {
      o[0][j] = fmaf(a0, uv8[j], o[0][j]);
      o[1][j] = fmaf(a1, uv8[j], o[1][j]);
    }
  }
#pragma unroll
  for (int ii = 0; ii < 2; ii++) {
    unsigned short* wp = win + ((size_t)(b * LL + tile * 64 + t2 + ii)) * DD + hh * 64 + tx * 8;
    ushort4 r0, r1;
    r0.x = f2bf(o[ii][0]); r0.y = f2bf(o[ii][1]); r0.z = f2bf(o[ii][2]); r0.w = f2bf(o[ii][3]);
    r1.x = f2bf(o[ii][4]); r1.y = f2bf(o[ii][5]); r1.z = f2bf(o[ii][6]); r1.w = f2bf(o[ii][7]);
    *(ushort4*)wp = r0;
    *(ushort4*)(wp + 4) = r1;
  }
}

// ------------------------------ LayerNorm ----------------------------------
__global__ __launch_bounds__(256) void ln_add(
    const float* __restrict__ A, const float* __restrict__ Bm,
    const float* __restrict__ gamma, const float* __restrict__ beta,
    float* __restrict__ out, unsigned short* __restrict__ outb) {
  const int row = blockIdx.x, tid = threadIdx.x;
  float4 va = ((const float4*)(A + (size_t)row * DD))[tid];
  float4 vb = ((const float4*)(Bm + (size_t)row * DD))[tid];
  float4 s4 = f4(va.x + vb.x, va.y + vb.y, va.z + vb.z, va.w + vb.w);
  float s = s4.x + s4.y + s4.z + s4.w;
  float ss = s4.x * s4.x + s4.y * s4.y + s4.z * s4.z + s4.w * s4.w;
  for (int o = 32; o; o >>= 1) { s += __shfl_xor(s, o); ss += __shfl_xor(ss, o); }
  __shared__ float red[8];
  int wid = tid >> 6;
  if ((tid & 63) == 0) { red[wid * 2] = s; red[wid * 2 + 1] = ss; }
  __syncthreads();
  float tot = red[0] + red[2] + red[4] + red[6];
  float tots = red[1] + red[3] + red[5] + red[7];
  float mu = tot * (1.0f / 1024.0f);
  float var = tots * (1.0f / 1024.0f) - mu * mu;
  float rstd = rsqrtf(var + 1e-5f);
  float4 g = ((const float4*)gamma)[tid];
  float4 be = ((const float4*)beta)[tid];
  float4 o = f4((s4.x - mu) * rstd * g.x + be.x, (s4.y - mu) * rstd * g.y + be.y,
                (s4.z - mu) * rstd * g.z + be.z, (s4.w - mu) * rstd * g.w + be.w);
  ((float4*)(out + (size_t)row * DD))[tid] = o;
  if (outb) {
    ushort4 r;
    r.x = f2bf(o.x); r.y = f2bf(o.y); r.z = f2bf(o.z); r.w = f2bf(o.w);
    ((ushort4*)(outb + (size_t)row * DD))[tid] = r;
  }
}

// ------------------------------ launch -------------------------------------
extern "C" void kernel_launch(void* const* d_in, const int* in_sizes, int n_in,
                              void* d_out, int out_size, void* d_ws, size_t ws_size,
                              hipStream_t stream) {
  (void)in_sizes; (void)n_in; (void)out_size; (void)ws_size;
  const float* x      = (const float*)d_in[0];
  const float* kv0    = (const float*)d_in[1];
  const float* kst0   = (const float*)d_in[2];
  const float* kbuf   = (const float*)d_in[3];
  const float* vbufw  = (const float*)d_in[4];
  const float* Wq_lin = (const float*)d_in[5];
  const float* bq_lin = (const float*)d_in[6];
  const float* Wk_lin = (const float*)d_in[7];
  const float* bk_lin = (const float*)d_in[8];
  const float* Wv_lin = (const float*)d_in[9];
  const float* bv_lin = (const float*)d_in[10];
  const float* Wo_lin = (const float*)d_in[11];
  const float* bo_lin = (const float*)d_in[12];
  const float* Wq     = (const float*)d_in[13];
  const float* bq     = (const float*)d_in[14];
  const float* Wk     = (const float*)d_in[15];
  const float* bk     = (const float*)d_in[16];
  const float* Wv     = (const float*)d_in[17];
  const float* bv     = (const float*)d_in[18];
  const float* Wo     = (const float*)d_in[19];
  const float* bo     = (const float*)d_in[20];
  const float* gamma  = (const float*)d_in[21];
  const float* beta   = (const float*)d_in[22];

  float* out = (float*)d_out;
  float* kv_out  = out + 8388608;
  float* kst_out = out + 8388608 + 1118208;

  float* ws = (float*)d_ws;
  const size_t MF = 1024 * 1024;
  // fp32 buffers
  float* qlin  = ws;                       // [0,2) MF
  float* klin  = ws + 2 * MF;              // [2,4)
  float* v     = ws + 4 * MF;              // [4,12)
  float* KVc   = ws + 12 * MF;             // [12,29.06)
  float* kstc  = ws + 12 * MF + 17891328;  // [29.06,29.33)
  float* tmp   = ws + 14155776;            // 13.5 MF, [13.5,21.5)
  float* x1    = ws + 22544384;            // 21.5 MF, [21.5,29.5)
  float* q2    = ws;                       // [0,8)   (qlin/klin/v dead)
  float* klast = ws + 30932992;            // 29.5 MF
  float* vlast = klast + 4096;
  float* tmp2  = tmp;                      // [13.5,21.5) (tmp dead)
  // bf16 buffers (ushort)
  unsigned short* x_bf    = (unsigned short*)(ws + 35 * MF);   // [35,39) MF
  unsigned short* WtQL    = (unsigned short*)(ws + 12 * MF);   // pre-phaseA region
  unsigned short* WtKL    = WtQL + 262144;
  unsigned short* WtVL    = WtQL + 524288;                     // +0.5 MF worth
  unsigned short* outs_bf = (unsigned short*)(ws + 31 * MF);   // [31,35)
  unsigned short* WtO1    = (unsigned short*)(ws + 12 * MF);   // post-phaseC region
  unsigned short* WtQ2    = WtO1 + 1048576;                    // 12.5 MF
  unsigned short* WtO2    = WtO1 + 2097152;                    // 13.0 MF
  unsigned short* x1b     = (unsigned short*)(ws + 31 * MF);   // reuse (outs_bf dead)
  unsigned short* winb    = (unsigned short*)(ws + 8 * MF);    // [8,12) (v dead)

  dim3 blk(256);
  // casts for first GEMM group
  cast_bf16<<<8192, blk, 0, stream>>>(x, x_bf, 2097152);
  castT<<<dim3(16, 4), blk, 0, stream>>>(Wq_lin, WtQL, 1024, 256);
  castT<<<dim3(16, 4), blk, 0, stream>>>(Wk_lin, WtKL, 1024, 256);
  castT<<<dim3(16, 16), blk, 0, stream>>>(Wv_lin, WtVL, 1024, 1024);
  gemm_mfma<<<dim3(64, 2), blk, 0, stream>>>(x_bf, WtQL, bq_lin, qlin, 8192, 256, 1024);
  gemm_mfma<<<dim3(64, 2), blk, 0, stream>>>(x_bf, WtKL, bk_lin, klin, 8192, 256, 1024);
  gemm_mfma<<<dim3(64, 8), blk, 0, stream>>>(x_bf, WtVL, bv_lin, v, 8192, 1024, 1024);
  // linear attention
  phaseA<<<1024, blk, 0, stream>>>(klin, v, KVc, kstc);
  phaseB<<<64, blk, 0, stream>>>(KVc, kstc, kv0, kst0, kv_out, kst_out);
  phaseC<<<1024, blk, 0, stream>>>(qlin, klin, v, KVc, kstc, outs_bf);
  // casts for second GEMM group (KVc region dead now)
  castT<<<dim3(16, 16), blk, 0, stream>>>(Wo_lin, WtO1, 1024, 1024);
  castT<<<dim3(16, 16), blk, 0, stream>>>(Wq, WtQ2, 1024, 1024);
  castT<<<dim3(16, 16), blk, 0, stream>>>(Wo, WtO2, 1024, 1024);
  gemm_mfma<<<dim3(64, 8), blk, 0, stream>>>(outs_bf, WtO1, bo_lin, tmp, 8192, 1024, 1024);
  ln_add<<<8192, blk, 0, stream>>>(x, tmp, gamma, beta, x1, x1b);
  gemm_mfma<<<dim3(64, 8), blk, 0, stream>>>(x1b, WtQ2, bq, q2, 8192, 1024, 1024);
  lastrow_qkv<<<32, blk, 0, stream>>>(x1, Wk, bk, Wv, bv, klast, vlast);
  window_attn<<<2048, blk, 0, stream>>>(q2, klast, vlast, kbuf, vbufw, winb);
  gemm_mfma<<<dim3(64, 8), blk, 0, stream>>>(winb, WtO2, bo, tmp2, 8192, 1024, 1024);
  ln_add<<<8192, blk, 0, stream>>>(x1, tmp2, gamma, beta, out, (unsigned short*)0);
}

// Round 4
// 684.011 us; speedup vs baseline: 2.5663x; 1.1754x over previous
//
#include <hip/hip_runtime.h>
#include <math.h>

// ---------------------------------------------------------------------------
// BasedBlock: B=4 L=2048 d=1024 h=16 f=16 hd=64 w=64, D=1+f+f*f=273
// Round 3: phaseA/phaseC -> bf16 MFMA.
//   phaseC: inter = Qf[128x288]@KV'[288x80] (col64 = kst -> den), intra =
//     u-MFMA (K=16 pad 32) -> poly/mask -> S bf16 in LDS -> S@V' (col64 = 1
//     -> den), shared accumulators. LDS 53KB, granule-XOR swizzles.
//   phaseA: KVc = Kf^T[320x128]@V'[128x80], Kf^T generated in A-layout in
//     LDS, V transposed via LDS staging, kst via ones-column. LDS 44KB.
//   qlin/klin/v now bf16 (gemm_mfma bf16-output mode).
// ---------------------------------------------------------------------------

#define LL 2048
#define DD 1024
#define DFEAT 273
#define NC 16
#define CHUNK 128

typedef __attribute__((ext_vector_type(8))) short short8;
typedef __attribute__((ext_vector_type(4))) float f32x4;

__device__ __forceinline__ float4 f4(float a, float b, float c, float d) {
  float4 r; r.x = a; r.y = b; r.z = c; r.w = d; return r;
}

__device__ __forceinline__ unsigned short f2bf(float f) {
  union { float f; unsigned u; } v; v.f = f;
  unsigned r = v.u + 0x7fffu + ((v.u >> 16) & 1u);
  return (unsigned short)(r >> 16);
}

__device__ __forceinline__ float bf2f(unsigned short u) {
  union { unsigned u; float f; } v; v.u = ((unsigned)u) << 16; return v.f;
}

// --------------------------- cast kernels ----------------------------------
__global__ __launch_bounds__(256) void cast_bf16(
    const float* __restrict__ in, unsigned short* __restrict__ o, int n4) {
  int i = blockIdx.x * 256 + threadIdx.x;
  if (i < n4) {
    float4 v = ((const float4*)in)[i];
    ushort4 r;
    r.x = f2bf(v.x); r.y = f2bf(v.y); r.z = f2bf(v.z); r.w = f2bf(v.w);
    ((ushort4*)o)[i] = r;
  }
}

// W[K][N] fp32 -> Wt[N][K] bf16
__global__ __launch_bounds__(256) void castT(
    const float* __restrict__ W, unsigned short* __restrict__ Wt, int K, int N) {
  __shared__ float t[64][65];
  int k0 = blockIdx.x * 64, n0 = blockIdx.y * 64;
  int tid = threadIdx.x;
#pragma unroll
  for (int p = 0; p < 16; p++) {
    int idx = p * 256 + tid;
    int r = idx >> 6, c = idx & 63;
    t[r][c] = W[(size_t)(k0 + r) * N + n0 + c];
  }
  __syncthreads();
#pragma unroll
  for (int p = 0; p < 16; p++) {
    int idx = p * 256 + tid;
    int rn = idx >> 6, ck = idx & 63;
    Wt[(size_t)(n0 + rn) * K + k0 + ck] = f2bf(t[ck][rn]);
  }
}

// --------------------------- MFMA GEMM -------------------------------------
// C = A[M,K](bf16) @ Bt[N,K]^T + bias. Output fp32 (C) or bf16 (Cb).
__global__ __launch_bounds__(256) void gemm_mfma(
    const unsigned short* __restrict__ A, const unsigned short* __restrict__ Bt,
    const float* __restrict__ bias, float* __restrict__ C,
    unsigned short* __restrict__ Cb, int M, int N, int K) {
  __shared__ unsigned short As[128 * 64];
  __shared__ unsigned short Bs[128 * 64];
  const int tid = threadIdx.x;
  const int lane = tid & 63, w = tid >> 6;
  const int row0 = blockIdx.x * 128, col0 = blockIdx.y * 128;
  const int wm0 = (w & 1) * 64, wn0 = (w >> 1) * 64;
  const int lr = lane >> 3;
  const int gc = (lane & 7) ^ lr;
  const unsigned short* aP = A + (size_t)(row0 + w * 32 + lr) * K + gc * 8;
  const unsigned short* bP = Bt + (size_t)(col0 + w * 32 + lr) * K + gc * 8;
  unsigned short* asW = As + w * 2048;
  unsigned short* bsW = Bs + w * 2048;
  const int m15 = lane & 15, quad = lane >> 4;
  f32x4 acc[4][4] = {};
  for (int k0 = 0; k0 < K; k0 += 64) {
#pragma unroll
    for (int i = 0; i < 4; i++) {
      __builtin_amdgcn_global_load_lds(
          (const __attribute__((address_space(1))) unsigned int*)(const void*)(aP + (size_t)(i * 8) * K + k0),
          (__attribute__((address_space(3))) unsigned int*)(void*)(asW + i * 512), 16, 0, 0);
      __builtin_amdgcn_global_load_lds(
          (const __attribute__((address_space(1))) unsigned int*)(const void*)(bP + (size_t)(i * 8) * K + k0),
          (__attribute__((address_space(3))) unsigned int*)(void*)(bsW + i * 512), 16, 0, 0);
    }
    __syncthreads();
#pragma unroll
    for (int ks = 0; ks < 2; ks++) {
      short8 aF[4], bF[4];
#pragma unroll
      for (int mi = 0; mi < 4; mi++) {
        int r = wm0 + mi * 16 + m15;
        int g = (ks * 4 + quad) ^ (r & 7);
        aF[mi] = *(const short8*)(As + r * 64 + g * 8);
      }
#pragma unroll
      for (int ni = 0; ni < 4; ni++) {
        int r = wn0 + ni * 16 + m15;
        int g = (ks * 4 + quad) ^ (r & 7);
        bF[ni] = *(const short8*)(Bs + r * 64 + g * 8);
      }
#pragma unroll
      for (int mi = 0; mi < 4; mi++)
#pragma unroll
        for (int ni = 0; ni < 4; ni++)
          acc[mi][ni] = __builtin_amdgcn_mfma_f32_16x16x32_bf16(
              aF[mi], bF[ni], acc[mi][ni], 0, 0, 0);
    }
    __syncthreads();
  }
#pragma unroll
  for (int mi = 0; mi < 4; mi++)
#pragma unroll
    for (int ni = 0; ni < 4; ni++) {
      int col = col0 + wn0 + ni * 16 + m15;
      float bb = bias[col];
#pragma unroll
      for (int r = 0; r < 4; r++) {
        int row = row0 + wm0 + mi * 16 + quad * 4 + r;
        float val = acc[mi][ni][r] + bb;
        if (Cb) Cb[(size_t)row * N + col] = f2bf(val);
        else C[(size_t)row * N + col] = val;
      }
    }
}

// ------------------------------ phase A (MFMA) -----------------------------
// Per (bh,ck): KVc[r][c] = sum_t Kf[t][r] V[t][c]; kstc[r] = sum_t Kf[t][r].
// D[320x80] = A(Kf^T)[320x128] @ B(V'^T)[80x128]^T; col 64 of V' = ones.
__global__ __launch_bounds__(256, 2) void phaseA_mfma(
    const unsigned short* __restrict__ klin, const unsigned short* __restrict__ vb,
    float* __restrict__ KVc, float* __restrict__ kstc) {
  __shared__ unsigned short kT[16 * 128];   // [i][t] bf16, 4KB
  __shared__ unsigned short B2[80 * 128];   // V'^T [c][t] swizzled, 20KB
  __shared__ unsigned short Au[320 * 32];   // Kf^T t-slice [r][t32] swizzled, 20KB
  unsigned short* vstage = Au;              // [32][64] overlay
  const int tid = threadIdx.x, lane = tid & 63, w = tid >> 6;
  const int m15 = lane & 15, quad = lane >> 4;
  const int bh = blockIdx.x >> 4, ck = blockIdx.x & 15;
  const int b = bh >> 4, hh = bh & 15;
  const int t0 = ck * CHUNK;
  {  // kT[i][t] transposed load
    int r = tid >> 1, half = tid & 1;
    short8 kv = *(const short8*)(klin + ((size_t)(b * LL + t0 + r)) * 256 + hh * 16 + half * 8);
#pragma unroll
    for (int j = 0; j < 8; j++) kT[(half * 8 + j) * 128 + r] = ((unsigned short*)&kv)[j];
  }
  // build B2 (V'^T) in 4 t-sub-slices via vstage
  for (int ss = 0; ss < 4; ++ss) {
    __syncthreads();
    {
      int sl = tid >> 3, c8 = (tid & 7) * 8;
      *(short8*)&vstage[sl * 64 + c8] =
          *(const short8*)(vb + ((size_t)(b * LL + t0 + ss * 32 + sl)) * DD + hh * 64 + c8);
    }
    __syncthreads();
    for (int id = tid; id < 320; id += 256) {
      int c = id >> 2, gg = id & 3;
      short8 vv;
      unsigned short* pv = (unsigned short*)&vv;
#pragma unroll
      for (int j = 0; j < 8; j++) {
        int sl = gg * 8 + j;
        pv[j] = (c < 64) ? vstage[sl * 64 + c]
                         : (c == 64 ? (unsigned short)0x3F80 : (unsigned short)0);
      }
      int g = ss * 4 + gg;
      int p = g ^ (c & 7);
      *(short8*)&B2[c * 128 + p * 8] = vv;
    }
  }
  __syncthreads();
  f32x4 acc[5][5] = {};
  for (int ks = 0; ks < 4; ++ks) {
    // generate Au = Kf^T slice [320][32]
    for (int id = tid; id < 1280; id += 256) {
      int r = id >> 2, g = id & 3;
      short8 vv;
      unsigned short* pv = (unsigned short*)&vv;
      if (r == 0) {
#pragma unroll
        for (int j = 0; j < 8; j++) pv[j] = 0x3F80;
      } else if (r < 17) {
        short8 kr = *(const short8*)&kT[(r - 1) * 128 + ks * 32 + g * 8];
#pragma unroll
        for (int j = 0; j < 8; j++)
          pv[j] = f2bf(bf2f(((unsigned short*)&kr)[j]) * 0.5f);
      } else if (r < DFEAT) {
        int ij = r - 17;
        short8 ki = *(const short8*)&kT[(ij >> 4) * 128 + ks * 32 + g * 8];
        short8 kj = *(const short8*)&kT[(ij & 15) * 128 + ks * 32 + g * 8];
#pragma unroll
        for (int j = 0; j < 8; j++)
          pv[j] = f2bf(bf2f(((unsigned short*)&ki)[j]) * bf2f(((unsigned short*)&kj)[j]) *
                       0.17677669529663687f);
      } else {
#pragma unroll
        for (int j = 0; j < 8; j++) pv[j] = 0;
      }
      int p = g ^ (r & 3);
      *(short8*)&Au[r * 32 + p * 8] = vv;
    }
    __syncthreads();
    short8 aF[5], bF[5];
#pragma unroll
    for (int mi = 0; mi < 5; mi++) {
      int r = (w * 5 + mi) * 16 + m15;
      int p = quad ^ (r & 3);
      aF[mi] = *(const short8*)&Au[r * 32 + p * 8];
    }
#pragma unroll
    for (int ni = 0; ni < 5; ni++) {
      int c = ni * 16 + m15;
      int p = (ks * 4 + quad) ^ (c & 7);
      bF[ni] = *(const short8*)&B2[c * 128 + p * 8];
    }
#pragma unroll
    for (int mi = 0; mi < 5; mi++)
#pragma unroll
      for (int ni = 0; ni < 5; ni++)
        acc[mi][ni] = __builtin_amdgcn_mfma_f32_16x16x32_bf16(
            aF[mi], bF[ni], acc[mi][ni], 0, 0, 0);
    __syncthreads();
  }
  const size_t cb = ((size_t)bh * NC + ck) * (DFEAT * 64);
  const size_t kb = ((size_t)bh * NC + ck) * DFEAT;
#pragma unroll
  for (int mi = 0; mi < 5; mi++) {
#pragma unroll
    for (int rr = 0; rr < 4; rr++) {
      int r = (w * 5 + mi) * 16 + quad * 4 + rr;
      if (r < DFEAT) {
#pragma unroll
        for (int ni = 0; ni < 4; ni++)
          KVc[cb + (size_t)r * 64 + ni * 16 + m15] = acc[mi][ni][rr];
        if (m15 == 0) kstc[kb + r] = acc[mi][4][rr];
      }
    }
  }
}

// ------------------------------ phase B ------------------------------------
__global__ __launch_bounds__(256) void phaseB(
    float* __restrict__ KVc, float* __restrict__ kstc,
    const float* __restrict__ kv0, const float* __restrict__ kst0,
    float* __restrict__ kv_out, float* __restrict__ kst_out) {
  const int bh = blockIdx.x, tid = threadIdx.x;
  for (int e = tid; e < DFEAT * 64; e += 256) {
    float acc = kv0[(size_t)bh * (DFEAT * 64) + e];
    for (int ck = 0; ck < NC; ++ck) {
      size_t idx = ((size_t)bh * NC + ck) * (DFEAT * 64) + e;
      float t = KVc[idx]; KVc[idx] = acc; acc += t;
    }
    kv_out[(size_t)bh * (DFEAT * 64) + e] = acc;
  }
  for (int e = tid; e < DFEAT; e += 256) {
    float acc = kst0[bh * DFEAT + e];
    for (int ck = 0; ck < NC; ++ck) {
      size_t idx = ((size_t)bh * NC + ck) * DFEAT + e;
      float t = kstc[idx]; kstc[idx] = acc; acc += t;
    }
    kst_out[bh * DFEAT + e] = acc;
  }
}

// ------------------------------ phase C (MFMA) -----------------------------
// Per (bh,ck): out[t][c] = (Qf@KV' + S@V')[t][c] / den[t]; den = col 64.
__global__ __launch_bounds__(256, 2) void phaseC_mfma(
    const unsigned short* __restrict__ qlin, const unsigned short* __restrict__ klin,
    const unsigned short* __restrict__ vb, const float* __restrict__ KVc,
    const float* __restrict__ kstc, unsigned short* __restrict__ outs) {
  __shared__ unsigned short q_b[128 * 16];   // 4KB
  __shared__ unsigned short k_b[128 * 16];   // 4KB
  __shared__ unsigned short S_l[128 * 128];  // 32KB, granule swz g^(t&7)
  __shared__ unsigned short Af[128 * 32];    // 8KB (pass1 Qf / pass2 vstage)
  __shared__ unsigned short Bf[80 * 32];     // 5KB, swz g^(c&3)
  unsigned short* vstage = Af;               // [32][64] overlay
  const int tid = threadIdx.x, lane = tid & 63, w = tid >> 6;
  const int m15 = lane & 15, quad = lane >> 4;
  const int bh = blockIdx.x >> 4, ck = blockIdx.x & 15;
  const int b = bh >> 4, hh = bh & 15;
  const int t0 = ck * CHUNK;
  const float* KVb = KVc + ((size_t)bh * NC + ck) * (DFEAT * 64);
  const float* kstb = kstc + ((size_t)bh * NC + ck) * DFEAT;
  {
    int r = tid >> 1, half = tid & 1;
    *(short8*)&q_b[r * 16 + half * 8] =
        *(const short8*)(qlin + ((size_t)(b * LL + t0 + r)) * 256 + hh * 16 + half * 8);
    *(short8*)&k_b[r * 16 + half * 8] =
        *(const short8*)(klin + ((size_t)(b * LL + t0 + r)) * 256 + hh * 16 + half * 8);
  }
  __syncthreads();
  // cache own q row for Qf generation (row r = tid>>1)
  float qv[16];
  {
    int r = tid >> 1;
    short8 q0 = *(const short8*)&q_b[r * 16];
    short8 q1 = *(const short8*)&q_b[r * 16 + 8];
#pragma unroll
    for (int j = 0; j < 8; j++) {
      qv[j] = bf2f(((unsigned short*)&q0)[j]);
      qv[8 + j] = bf2f(((unsigned short*)&q1)[j]);
    }
  }
  f32x4 acc[2][5] = {};
  // ---- pass 1: inter (Qf @ KV'), 9 feature-slices of 32 ----
  for (int ks = 0; ks < 9; ++ks) {
    int fs = ks * 32;
    {  // generate Af (Qf slice): row r = tid>>1, granules (tid&1)*2 + {0,1}
      int r = tid >> 1;
#pragma unroll
      for (int gg = 0; gg < 2; gg++) {
        int g = (tid & 1) * 2 + gg;
        short8 vv;
        unsigned short* pv = (unsigned short*)&vv;
#pragma unroll
        for (int j = 0; j < 8; j++) {
          int f = fs + g * 8 + j;
          float val;
          if (f == 0) val = 1.0f;
          else if (f < 17) val = qv[f - 1] * 0.5f;
          else if (f < DFEAT) {
            int ij = f - 17;
            val = qv[ij >> 4] * qv[ij & 15] * 0.17677669529663687f;
          } else val = 0.0f;
          pv[j] = f2bf(val);
        }
        int p = g ^ (r & 3);
        *(short8*)&Af[r * 32 + p * 8] = vv;
      }
    }
    for (int id = tid; id < 320; id += 256) {  // stage Bf = KV' slice
      int c = id >> 2, g = id & 3;
      short8 vv;
      unsigned short* pv = (unsigned short*)&vv;
#pragma unroll
      for (int j = 0; j < 8; j++) {
        int f = fs + g * 8 + j;
        float val = 0.0f;
        if (f < DFEAT) {
          if (c < 64) val = KVb[(size_t)f * 64 + c];
          else if (c == 64) val = kstb[f];
        }
        pv[j] = f2bf(val);
      }
      int p = g ^ (c & 3);
      *(short8*)&Bf[c * 32 + p * 8] = vv;
    }
    __syncthreads();
    short8 aF[2], bF[5];
#pragma unroll
    for (int mi = 0; mi < 2; mi++) {
      int r = w * 32 + mi * 16 + m15;
      int p = quad ^ (r & 3);
      aF[mi] = *(const short8*)&Af[r * 32 + p * 8];
    }
#pragma unroll
    for (int ni = 0; ni < 5; ni++) {
      int c = ni * 16 + m15;
      int p = quad ^ (c & 3);
      bF[ni] = *(const short8*)&Bf[c * 32 + p * 8];
    }
#pragma unroll
    for (int mi = 0; mi < 2; mi++)
#pragma unroll
      for (int ni = 0; ni < 5; ni++)
        acc[mi][ni] = __builtin_amdgcn_mfma_f32_16x16x32_bf16(
            aF[mi], bF[ni], acc[mi][ni], 0, 0, 0);
    __syncthreads();
  }
  // ---- intra: u = q@k^T via MFMA (K=16 pad 32), poly+mask -> S_l ----
  {
    short8 z = {0, 0, 0, 0, 0, 0, 0, 0};
    short8 bU[8];
#pragma unroll
    for (int sn = 0; sn < 8; sn++) {
      int s = sn * 16 + m15;
      bU[sn] = (quad < 2) ? *(const short8*)&k_b[s * 16 + quad * 8] : z;
    }
#pragma unroll
    for (int mi = 0; mi < 2; mi++) {
      int t_row = w * 32 + mi * 16 + m15;
      short8 aU = (quad < 2) ? *(const short8*)&q_b[t_row * 16 + quad * 8] : z;
#pragma unroll
      for (int sn = 0; sn < 8; sn++) {
        f32x4 zz = {0.f, 0.f, 0.f, 0.f};
        f32x4 u = __builtin_amdgcn_mfma_f32_16x16x32_bf16(aU, bU[sn], zz, 0, 0, 0);
        int s = sn * 16 + m15;
        int gRow = s >> 3;
#pragma unroll
        for (int rr = 0; rr < 4; rr++) {
          int t = w * 32 + mi * 16 + quad * 4 + rr;
          float uu = u[rr];
          float sv = (s <= t) ? fmaf(uu, fmaf(uu, 0.03125f, 0.25f), 1.0f) : 0.0f;
          int p = gRow ^ (t & 7);
          S_l[t * 128 + p * 8 + (s & 7)] = f2bf(sv);
        }
      }
    }
  }
  // ---- pass 2: intra S @ V', 4 s-slices of 32 ----
  for (int ks = 0; ks < 4; ++ks) {
    {
      int sl = tid >> 3, c8 = (tid & 7) * 8;
      *(short8*)&vstage[sl * 64 + c8] =
          *(const short8*)(vb + ((size_t)(b * LL + t0 + ks * 32 + sl)) * DD + hh * 64 + c8);
    }
    __syncthreads();
    for (int id = tid; id < 320; id += 256) {
      int c = id >> 2, g = id & 3;
      short8 vv;
      unsigned short* pv = (unsigned short*)&vv;
#pragma unroll
      for (int j = 0; j < 8; j++) {
        int sl = g * 8 + j;
        pv[j] = (c < 64) ? vstage[sl * 64 + c]
                         : (c == 64 ? (unsigned short)0x3F80 : (unsigned short)0);
      }
      int p = g ^ (c & 3);
      *(short8*)&Bf[c * 32 + p * 8] = vv;
    }
    __syncthreads();
    short8 aF[2], bF[5];
#pragma unroll
    for (int mi = 0; mi < 2; mi++) {
      int t = w * 32 + mi * 16 + m15;
      int p = (ks * 4 + quad) ^ (t & 7);
      aF[mi] = *(const short8*)&S_l[t * 128 + p * 8];
    }
#pragma unroll
    for (int ni = 0; ni < 5; ni++) {
      int c = ni * 16 + m15;
      int p = quad ^ (c & 3);
      bF[ni] = *(const short8*)&Bf[c * 32 + p * 8];
    }
#pragma unroll
    for (int mi = 0; mi < 2; mi++)
#pragma unroll
      for (int ni = 0; ni < 5; ni++)
        acc[mi][ni] = __builtin_amdgcn_mfma_f32_16x16x32_bf16(
            aF[mi], bF[ni], acc[mi][ni], 0, 0, 0);
    __syncthreads();
  }
  // ---- epilogue: divide by den (col 64) and store bf16 ----
#pragma unroll
  for (int mi = 0; mi < 2; mi++) {
#pragma unroll
    for (int rr = 0; rr < 4; rr++) {
      float den = __shfl(acc[mi][4][rr], (lane & 48));
      float inv = 1.0f / (den + 1e-6f);
      int t = w * 32 + mi * 16 + quad * 4 + rr;
      unsigned short* op = outs + ((size_t)(b * LL + t0 + t)) * DD + hh * 64;
#pragma unroll
      for (int ni = 0; ni < 4; ni++)
        op[ni * 16 + m15] = f2bf(acc[mi][ni][rr] * inv);
    }
  }
}

// --------------------------- last-row k2/v2 --------------------------------
__global__ __launch_bounds__(256) void lastrow_qkv(
    const float* __restrict__ x1,
    const float* __restrict__ Wk, const float* __restrict__ bk,
    const float* __restrict__ Wv, const float* __restrict__ bv,
    float* __restrict__ klast, float* __restrict__ vlast) {
  int gid = blockIdx.x * 256 + threadIdx.x;
  int which = gid >> 12;
  int b = (gid >> 10) & 3;
  int n = gid & 1023;
  const float* W = which ? Wv : Wk;
  const float* xr = x1 + ((size_t)(b * LL + LL - 1)) * DD;
  float s = 0.f;
  for (int k = 0; k < 1024; k++) s = fmaf(xr[k], W[(size_t)k * 1024 + n], s);
  s += which ? bv[n] : bk[n];
  (which ? vlast : klast)[b * 1024 + n] = s;
}

// --------------------------- window attention ------------------------------
__global__ __launch_bounds__(256) void window_attn(
    const float* __restrict__ q2, const float* __restrict__ klast,
    const float* __restrict__ vlast, const float* __restrict__ kbuf,
    const float* __restrict__ vbufw, unsigned short* __restrict__ win) {
  __shared__ float ukT[64][68];
  __shared__ float uvs[64][68];
  __shared__ float S[64][68];
  const int tid = threadIdx.x;
  const int bh = blockIdx.x >> 5, tile = blockIdx.x & 31;
  const int b = bh >> 4, hh = bh & 15;
#pragma unroll
  for (int p = 0; p < 4; p++) {
    int g = tid + p * 256;
    int wi = g >> 4, d4 = (g & 15) * 4;
    const float* kp = (wi < 63) ? (kbuf + ((size_t)hh * 64 + wi + 1) * 64 + d4)
                                : (klast + (size_t)b * 1024 + hh * 64 + d4);
    float4 kk = *(const float4*)kp;
    ukT[d4 + 0][wi] = kk.x; ukT[d4 + 1][wi] = kk.y;
    ukT[d4 + 2][wi] = kk.z; ukT[d4 + 3][wi] = kk.w;
    const float* vp = (wi < 63) ? (vbufw + ((size_t)hh * 64 + wi + 1) * 64 + d4)
                                : (vlast + (size_t)b * 1024 + hh * 64 + d4);
    *(float4*)&uvs[wi][d4] = *(const float4*)vp;
    const float* qp = q2 + ((size_t)(b * LL + tile * 64 + wi)) * DD + hh * 64 + d4;
    *(float4*)&S[wi][d4] = *(const float4*)qp;
  }
  __syncthreads();
  const int tx = tid & 7, ty = tid >> 3;
  const int t2 = ty * 2;
  float a[2][8] = {};
  for (int d = 0; d < 64; ++d) {
    float q0 = S[t2][d], q1 = S[t2 + 1][d];
    float4 u0 = *(const float4*)&ukT[d][tx * 8];
    float4 u1 = *(const float4*)&ukT[d][tx * 8 + 4];
    float uk8[8] = {u0.x, u0.y, u0.z, u0.w, u1.x, u1.y, u1.z, u1.w};
#pragma unroll
    for (int j = 0; j < 8; j++) {
      a[0][j] = fmaf(q0, uk8[j], a[0][j]);
      a[1][j] = fmaf(q1, uk8[j], a[1][j]);
    }
  }
  __syncthreads();
#pragma unroll
  for (int ii = 0; ii < 2; ii++) {
    *(float4*)&S[t2 + ii][tx * 8] =
        f4(a[ii][0] * 0.125f, a[ii][1] * 0.125f, a[ii][2] * 0.125f, a[ii][3] * 0.125f);
    *(float4*)&S[t2 + ii][tx * 8 + 4] =
        f4(a[ii][4] * 0.125f, a[ii][5] * 0.125f, a[ii][6] * 0.125f, a[ii][7] * 0.125f);
  }
  __syncthreads();
  if (tid < 64) {
    float v[64];
#pragma unroll
    for (int i = 0; i < 16; i++) *(float4*)&v[i * 4] = *(const float4*)&S[tid][i * 4];
    float m = v[0];
#pragma unroll
    for (int i = 1; i < 64; i++) m = fmaxf(m, v[i]);
    float l = 0.f;
#pragma unroll
    for (int i = 0; i < 64; i++) { v[i] = expf(v[i] - m); l += v[i]; }
    float inv = 1.0f / l;
#pragma unroll
    for (int i = 0; i < 16; i++)
      *(float4*)&S[tid][i * 4] =
          f4(v[i * 4] * inv, v[i * 4 + 1] * inv, v[i * 4 + 2] * inv, v[i * 4 + 3] * inv);
  }
  __syncthreads();
  float o[2][8] = {};
  for (int w = 0; w < 64; ++w) {
    float a0 = S[t2][w], a1 = S[t2 + 1][w];
    float4 x0 = *(const float4*)&uvs[w][tx * 8];
    float4 x1v = *(const float4*)&uvs[w][tx * 8 + 4];
    float uv8[8] = {x0.x, x0.y, x0.z, x0.w, x1v.x, x1v.y, x1v.z, x1v.w};
#pragma unroll
    for (int j = 0; j < 8; j++) {
      o[0][j] = fmaf(a0, uv8[j], o[0][j]);
      o[1][j] = fmaf(a1, uv8[j], o[1][j]);
    }
  }
#pragma unroll
  for (int ii = 0; ii < 2; ii++) {
    unsigned short* wp = win + ((size_t)(b * LL + tile * 64 + t2 + ii)) * DD + hh * 64 + tx * 8;
    ushort4 r0, r1;
    r0.x = f2bf(o[ii][0]); r0.y = f2bf(o[ii][1]); r0.z = f2bf(o[ii][2]); r0.w = f2bf(o[ii][3]);
    r1.x = f2bf(o[ii][4]); r1.y = f2bf(o[ii][5]); r1.z = f2bf(o[ii][6]); r1.w = f2bf(o[ii][7]);
    *(ushort4*)wp = r0;
    *(ushort4*)(wp + 4) = r1;
  }
}

// ------------------------------ LayerNorm ----------------------------------
__global__ __launch_bounds__(256) void ln_add(
    const float* __restrict__ A, const float* __restrict__ Bm,
    const float* __restrict__ gamma, const float* __restrict__ beta,
    float* __restrict__ out, unsigned short* __restrict__ outb) {
  const int row = blockIdx.x, tid = threadIdx.x;
  float4 va = ((const float4*)(A + (size_t)row * DD))[tid];
  float4 vb = ((const float4*)(Bm + (size_t)row * DD))[tid];
  float4 s4 = f4(va.x + vb.x, va.y + vb.y, va.z + vb.z, va.w + vb.w);
  float s = s4.x + s4.y + s4.z + s4.w;
  float ss = s4.x * s4.x + s4.y * s4.y + s4.z * s4.z + s4.w * s4.w;
  for (int o = 32; o; o >>= 1) { s += __shfl_xor(s, o); ss += __shfl_xor(ss, o); }
  __shared__ float red[8];
  int wid = tid >> 6;
  if ((tid & 63) == 0) { red[wid * 2] = s; red[wid * 2 + 1] = ss; }
  __syncthreads();
  float tot = red[0] + red[2] + red[4] + red[6];
  float tots = red[1] + red[3] + red[5] + red[7];
  float mu = tot * (1.0f / 1024.0f);
  float var = tots * (1.0f / 1024.0f) - mu * mu;
  float rstd = rsqrtf(var + 1e-5f);
  float4 g = ((const float4*)gamma)[tid];
  float4 be = ((const float4*)beta)[tid];
  float4 o = f4((s4.x - mu) * rstd * g.x + be.x, (s4.y - mu) * rstd * g.y + be.y,
                (s4.z - mu) * rstd * g.z + be.z, (s4.w - mu) * rstd * g.w + be.w);
  ((float4*)(out + (size_t)row * DD))[tid] = o;
  if (outb) {
    ushort4 r;
    r.x = f2bf(o.x); r.y = f2bf(o.y); r.z = f2bf(o.z); r.w = f2bf(o.w);
    ((ushort4*)(outb + (size_t)row * DD))[tid] = r;
  }
}

// ------------------------------ launch -------------------------------------
extern "C" void kernel_launch(void* const* d_in, const int* in_sizes, int n_in,
                              void* d_out, int out_size, void* d_ws, size_t ws_size,
                              hipStream_t stream) {
  (void)in_sizes; (void)n_in; (void)out_size; (void)ws_size;
  const float* x      = (const float*)d_in[0];
  const float* kv0    = (const float*)d_in[1];
  const float* kst0   = (const float*)d_in[2];
  const float* kbuf   = (const float*)d_in[3];
  const float* vbufw  = (const float*)d_in[4];
  const float* Wq_lin = (const float*)d_in[5];
  const float* bq_lin = (const float*)d_in[6];
  const float* Wk_lin = (const float*)d_in[7];
  const float* bk_lin = (const float*)d_in[8];
  const float* Wv_lin = (const float*)d_in[9];
  const float* bv_lin = (const float*)d_in[10];
  const float* Wo_lin = (const float*)d_in[11];
  const float* bo_lin = (const float*)d_in[12];
  const float* Wq     = (const float*)d_in[13];
  const float* bq     = (const float*)d_in[14];
  const float* Wk     = (const float*)d_in[15];
  const float* bk     = (const float*)d_in[16];
  const float* Wv     = (const float*)d_in[17];
  const float* bv     = (const float*)d_in[18];
  const float* Wo     = (const float*)d_in[19];
  const float* bo     = (const float*)d_in[20];
  const float* gamma  = (const float*)d_in[21];
  const float* beta   = (const float*)d_in[22];

  float* out = (float*)d_out;
  float* kv_out  = out + 8388608;
  float* kst_out = out + 8388608 + 1118208;

  float* ws = (float*)d_ws;
  const size_t MF = 1024 * 1024;
  unsigned short* qlin_b = (unsigned short*)(ws);            // [0,1) MF
  unsigned short* klin_b = (unsigned short*)(ws + 1 * MF);   // [1,2)
  unsigned short* v_b    = (unsigned short*)(ws + 2 * MF);   // [2,6)
  float* KVc   = ws + 6 * MF;                                // [6, ~23.1)
  float* kstc  = ws + 6 * MF + 17891328;                     // ~[23.1, 23.3)
  unsigned short* x_bf    = (unsigned short*)(ws + 24 * MF); // [24,28)
  unsigned short* outs_bf = (unsigned short*)(ws + 28 * MF); // [28,32)
  float* tmp   = ws + 6 * MF;                                // [6,14)  (KVc dead)
  float* x1    = ws + 14 * MF;                               // [14,22)
  unsigned short* x1b = (unsigned short*)(ws + 28 * MF);     // [28,32) (outs dead)
  float* q2    = ws;                                         // [0,8)   (qkv bf dead)
  unsigned short* winb = (unsigned short*)(ws + 8 * MF);     // [8,12)  (tmp dead)
  float* tmp2  = ws + 24 * MF;                               // [24,32) (x_bf/x1b dead)
  float* klast = ws + 32 * MF;
  float* vlast = klast + 4096;
  unsigned short* WtQL = (unsigned short*)(ws + 33 * MF);
  unsigned short* WtKL = WtQL + 262144;
  unsigned short* WtVL = WtQL + 524288;
  unsigned short* WtO1 = WtQL + 1572864;
  unsigned short* WtQ2 = WtQL + 2621440;
  unsigned short* WtO2 = WtQL + 3670016;

  dim3 blk(256);
  cast_bf16<<<8192, blk, 0, stream>>>(x, x_bf, 2097152);
  castT<<<dim3(16, 4), blk, 0, stream>>>(Wq_lin, WtQL, 1024, 256);
  castT<<<dim3(16, 4), blk, 0, stream>>>(Wk_lin, WtKL, 1024, 256);
  castT<<<dim3(16, 16), blk, 0, stream>>>(Wv_lin, WtVL, 1024, 1024);
  castT<<<dim3(16, 16), blk, 0, stream>>>(Wo_lin, WtO1, 1024, 1024);
  castT<<<dim3(16, 16), blk, 0, stream>>>(Wq, WtQ2, 1024, 1024);
  castT<<<dim3(16, 16), blk, 0, stream>>>(Wo, WtO2, 1024, 1024);
  gemm_mfma<<<dim3(64, 2), blk, 0, stream>>>(x_bf, WtQL, bq_lin, (float*)0, qlin_b, 8192, 256, 1024);
  gemm_mfma<<<dim3(64, 2), blk, 0, stream>>>(x_bf, WtKL, bk_lin, (float*)0, klin_b, 8192, 256, 1024);
  gemm_mfma<<<dim3(64, 8), blk, 0, stream>>>(x_bf, WtVL, bv_lin, (float*)0, v_b, 8192, 1024, 1024);
  phaseA_mfma<<<1024, blk, 0, stream>>>(klin_b, v_b, KVc, kstc);
  phaseB<<<64, blk, 0, stream>>>(KVc, kstc, kv0, kst0, kv_out, kst_out);
  phaseC_mfma<<<1024, blk, 0, stream>>>(qlin_b, klin_b, v_b, KVc, kstc, outs_bf);
  gemm_mfma<<<dim3(64, 8), blk, 0, stream>>>(outs_bf, WtO1, bo_lin, tmp, (unsigned short*)0, 8192, 1024, 1024);
  ln_add<<<8192, blk, 0, stream>>>(x, tmp, gamma, beta, x1, x1b);
  gemm_mfma<<<dim3(64, 8), blk, 0, stream>>>(x1b, WtQ2, bq, q2, (unsigned short*)0, 8192, 1024, 1024);
  lastrow_qkv<<<32, blk, 0, stream>>>(x1, Wk, bk, Wv, bv, klast, vlast);
  window_attn<<<2048, blk, 0, stream>>>(q2, klast, vlast, kbuf, vbufw, winb);
  gemm_mfma<<<dim3(64, 8), blk, 0, stream>>>(winb, WtO2, bo, tmp2, (unsigned short*)0, 8192, 1024, 1024);
  ln_add<<<8192, blk, 0, stream>>>(x1, tmp2, gamma, beta, out, (unsigned short*)0);
}

// Round 5
// 573.061 us; speedup vs baseline: 3.0632x; 1.1936x over previous
//
#include <hip/hip_runtime.h>
#include <math.h>

// ---------------------------------------------------------------------------
// BasedBlock: B=4 L=2048 d=1024 h=16 f=16 hd=64 w=64, D=1+f+f*f=273
// Round 4: phaseB parallelized + bf16 chunk-state path.
//   phaseA emits KVc/kstc in bf16; phaseB = 1 thread per ushort4 column
//   (1161 blocks), fp32 in-register scan, bf16 exclusive prefix out,
//   fp32 kv_out/kst_out; phaseC reads bf16 prefix directly (no cvt).
// ---------------------------------------------------------------------------

#define LL 2048
#define DD 1024
#define DFEAT 273
#define NC 16
#define CHUNK 128

typedef __attribute__((ext_vector_type(8))) short short8;
typedef __attribute__((ext_vector_type(4))) float f32x4;

__device__ __forceinline__ float4 f4(float a, float b, float c, float d) {
  float4 r; r.x = a; r.y = b; r.z = c; r.w = d; return r;
}

__device__ __forceinline__ unsigned short f2bf(float f) {
  union { float f; unsigned u; } v; v.f = f;
  unsigned r = v.u + 0x7fffu + ((v.u >> 16) & 1u);
  return (unsigned short)(r >> 16);
}

__device__ __forceinline__ float bf2f(unsigned short u) {
  union { unsigned u; float f; } v; v.u = ((unsigned)u) << 16; return v.f;
}

// --------------------------- cast kernels ----------------------------------
__global__ __launch_bounds__(256) void cast_bf16(
    const float* __restrict__ in, unsigned short* __restrict__ o, int n4) {
  int i = blockIdx.x * 256 + threadIdx.x;
  if (i < n4) {
    float4 v = ((const float4*)in)[i];
    ushort4 r;
    r.x = f2bf(v.x); r.y = f2bf(v.y); r.z = f2bf(v.z); r.w = f2bf(v.w);
    ((ushort4*)o)[i] = r;
  }
}

// W[K][N] fp32 -> Wt[N][K] bf16
__global__ __launch_bounds__(256) void castT(
    const float* __restrict__ W, unsigned short* __restrict__ Wt, int K, int N) {
  __shared__ float t[64][65];
  int k0 = blockIdx.x * 64, n0 = blockIdx.y * 64;
  int tid = threadIdx.x;
#pragma unroll
  for (int p = 0; p < 16; p++) {
    int idx = p * 256 + tid;
    int r = idx >> 6, c = idx & 63;
    t[r][c] = W[(size_t)(k0 + r) * N + n0 + c];
  }
  __syncthreads();
#pragma unroll
  for (int p = 0; p < 16; p++) {
    int idx = p * 256 + tid;
    int rn = idx >> 6, ck = idx & 63;
    Wt[(size_t)(n0 + rn) * K + k0 + ck] = f2bf(t[ck][rn]);
  }
}

// --------------------------- MFMA GEMM -------------------------------------
__global__ __launch_bounds__(256) void gemm_mfma(
    const unsigned short* __restrict__ A, const unsigned short* __restrict__ Bt,
    const float* __restrict__ bias, float* __restrict__ C,
    unsigned short* __restrict__ Cb, int M, int N, int K) {
  __shared__ unsigned short As[128 * 64];
  __shared__ unsigned short Bs[128 * 64];
  const int tid = threadIdx.x;
  const int lane = tid & 63, w = tid >> 6;
  const int row0 = blockIdx.x * 128, col0 = blockIdx.y * 128;
  const int wm0 = (w & 1) * 64, wn0 = (w >> 1) * 64;
  const int lr = lane >> 3;
  const int gc = (lane & 7) ^ lr;
  const unsigned short* aP = A + (size_t)(row0 + w * 32 + lr) * K + gc * 8;
  const unsigned short* bP = Bt + (size_t)(col0 + w * 32 + lr) * K + gc * 8;
  unsigned short* asW = As + w * 2048;
  unsigned short* bsW = Bs + w * 2048;
  const int m15 = lane & 15, quad = lane >> 4;
  f32x4 acc[4][4] = {};
  for (int k0 = 0; k0 < K; k0 += 64) {
#pragma unroll
    for (int i = 0; i < 4; i++) {
      __builtin_amdgcn_global_load_lds(
          (const __attribute__((address_space(1))) unsigned int*)(const void*)(aP + (size_t)(i * 8) * K + k0),
          (__attribute__((address_space(3))) unsigned int*)(void*)(asW + i * 512), 16, 0, 0);
      __builtin_amdgcn_global_load_lds(
          (const __attribute__((address_space(1))) unsigned int*)(const void*)(bP + (size_t)(i * 8) * K + k0),
          (__attribute__((address_space(3))) unsigned int*)(void*)(bsW + i * 512), 16, 0, 0);
    }
    __syncthreads();
#pragma unroll
    for (int ks = 0; ks < 2; ks++) {
      short8 aF[4], bF[4];
#pragma unroll
      for (int mi = 0; mi < 4; mi++) {
        int r = wm0 + mi * 16 + m15;
        int g = (ks * 4 + quad) ^ (r & 7);
        aF[mi] = *(const short8*)(As + r * 64 + g * 8);
      }
#pragma unroll
      for (int ni = 0; ni < 4; ni++) {
        int r = wn0 + ni * 16 + m15;
        int g = (ks * 4 + quad) ^ (r & 7);
        bF[ni] = *(const short8*)(Bs + r * 64 + g * 8);
      }
#pragma unroll
      for (int mi = 0; mi < 4; mi++)
#pragma unroll
        for (int ni = 0; ni < 4; ni++)
          acc[mi][ni] = __builtin_amdgcn_mfma_f32_16x16x32_bf16(
              aF[mi], bF[ni], acc[mi][ni], 0, 0, 0);
    }
    __syncthreads();
  }
#pragma unroll
  for (int mi = 0; mi < 4; mi++)
#pragma unroll
    for (int ni = 0; ni < 4; ni++) {
      int col = col0 + wn0 + ni * 16 + m15;
      float bb = bias[col];
#pragma unroll
      for (int r = 0; r < 4; r++) {
        int row = row0 + wm0 + mi * 16 + quad * 4 + r;
        float val = acc[mi][ni][r] + bb;
        if (Cb) Cb[(size_t)row * N + col] = f2bf(val);
        else C[(size_t)row * N + col] = val;
      }
    }
}

// ------------------------------ phase A (MFMA) -----------------------------
// Out: bf16 chunk sums KVc[bh][ck][r][c], kstc[bh][ck][r].
__global__ __launch_bounds__(256, 2) void phaseA_mfma(
    const unsigned short* __restrict__ klin, const unsigned short* __restrict__ vb,
    unsigned short* __restrict__ KVc, unsigned short* __restrict__ kstc) {
  __shared__ unsigned short kT[16 * 128];
  __shared__ unsigned short B2[80 * 128];
  __shared__ unsigned short Au[320 * 32];
  unsigned short* vstage = Au;
  const int tid = threadIdx.x, lane = tid & 63, w = tid >> 6;
  const int m15 = lane & 15, quad = lane >> 4;
  const int bh = blockIdx.x >> 4, ck = blockIdx.x & 15;
  const int b = bh >> 4, hh = bh & 15;
  const int t0 = ck * CHUNK;
  {
    int r = tid >> 1, half = tid & 1;
    short8 kv = *(const short8*)(klin + ((size_t)(b * LL + t0 + r)) * 256 + hh * 16 + half * 8);
#pragma unroll
    for (int j = 0; j < 8; j++) kT[(half * 8 + j) * 128 + r] = ((unsigned short*)&kv)[j];
  }
  for (int ss = 0; ss < 4; ++ss) {
    __syncthreads();
    {
      int sl = tid >> 3, c8 = (tid & 7) * 8;
      *(short8*)&vstage[sl * 64 + c8] =
          *(const short8*)(vb + ((size_t)(b * LL + t0 + ss * 32 + sl)) * DD + hh * 64 + c8);
    }
    __syncthreads();
    for (int id = tid; id < 320; id += 256) {
      int c = id >> 2, gg = id & 3;
      short8 vv;
      unsigned short* pv = (unsigned short*)&vv;
#pragma unroll
      for (int j = 0; j < 8; j++) {
        int sl = gg * 8 + j;
        pv[j] = (c < 64) ? vstage[sl * 64 + c]
                         : (c == 64 ? (unsigned short)0x3F80 : (unsigned short)0);
      }
      int g = ss * 4 + gg;
      int p = g ^ (c & 7);
      *(short8*)&B2[c * 128 + p * 8] = vv;
    }
  }
  __syncthreads();
  f32x4 acc[5][5] = {};
  for (int ks = 0; ks < 4; ++ks) {
    for (int id = tid; id < 1280; id += 256) {
      int r = id >> 2, g = id & 3;
      short8 vv;
      unsigned short* pv = (unsigned short*)&vv;
      if (r == 0) {
#pragma unroll
        for (int j = 0; j < 8; j++) pv[j] = 0x3F80;
      } else if (r < 17) {
        short8 kr = *(const short8*)&kT[(r - 1) * 128 + ks * 32 + g * 8];
#pragma unroll
        for (int j = 0; j < 8; j++)
          pv[j] = f2bf(bf2f(((unsigned short*)&kr)[j]) * 0.5f);
      } else if (r < DFEAT) {
        int ij = r - 17;
        short8 ki = *(const short8*)&kT[(ij >> 4) * 128 + ks * 32 + g * 8];
        short8 kj = *(const short8*)&kT[(ij & 15) * 128 + ks * 32 + g * 8];
#pragma unroll
        for (int j = 0; j < 8; j++)
          pv[j] = f2bf(bf2f(((unsigned short*)&ki)[j]) * bf2f(((unsigned short*)&kj)[j]) *
                       0.17677669529663687f);
      } else {
#pragma unroll
        for (int j = 0; j < 8; j++) pv[j] = 0;
      }
      int p = g ^ (r & 3);
      *(short8*)&Au[r * 32 + p * 8] = vv;
    }
    __syncthreads();
    short8 aF[5], bF[5];
#pragma unroll
    for (int mi = 0; mi < 5; mi++) {
      int r = (w * 5 + mi) * 16 + m15;
      int p = quad ^ (r & 3);
      aF[mi] = *(const short8*)&Au[r * 32 + p * 8];
    }
#pragma unroll
    for (int ni = 0; ni < 5; ni++) {
      int c = ni * 16 + m15;
      int p = (ks * 4 + quad) ^ (c & 7);
      bF[ni] = *(const short8*)&B2[c * 128 + p * 8];
    }
#pragma unroll
    for (int mi = 0; mi < 5; mi++)
#pragma unroll
      for (int ni = 0; ni < 5; ni++)
        acc[mi][ni] = __builtin_amdgcn_mfma_f32_16x16x32_bf16(
            aF[mi], bF[ni], acc[mi][ni], 0, 0, 0);
    __syncthreads();
  }
  const size_t cb = ((size_t)bh * NC + ck) * (DFEAT * 64);
  const size_t kb = ((size_t)bh * NC + ck) * DFEAT;
#pragma unroll
  for (int mi = 0; mi < 5; mi++) {
#pragma unroll
    for (int rr = 0; rr < 4; rr++) {
      int r = (w * 5 + mi) * 16 + quad * 4 + rr;
      if (r < DFEAT) {
#pragma unroll
        for (int ni = 0; ni < 4; ni++)
          KVc[cb + (size_t)r * 64 + ni * 16 + m15] = f2bf(acc[mi][ni][rr]);
        if (m15 == 0) kstc[kb + r] = f2bf(acc[mi][4][rr]);
      }
    }
  }
}

// ------------------------------ phase B ------------------------------------
// 1 thread per ushort4 column (KV) / per scalar column (kst); fp32 scan.
// Blocks [0,1092): KV. Blocks [1092,1161): kst.
__global__ __launch_bounds__(256) void phaseB2(
    const unsigned short* __restrict__ KVc, const unsigned short* __restrict__ kstc,
    const float* __restrict__ kv0, const float* __restrict__ kst0,
    unsigned short* __restrict__ KVp, unsigned short* __restrict__ kstp,
    float* __restrict__ kv_out, float* __restrict__ kst_out) {
  int gid = blockIdx.x * 256 + threadIdx.x;
  if (blockIdx.x < 1092) {
    int bh = gid / 4368, e4 = gid - bh * 4368;   // 4368 = 17472/4
    float4 acc = ((const float4*)kv0)[bh * 4368 + e4];
    size_t base = (size_t)bh * NC * 4368 + e4;
#pragma unroll
    for (int ck = 0; ck < NC; ck++) {
      size_t idx = base + (size_t)ck * 4368;
      ushort4 t = ((const ushort4*)KVc)[idx];
      ushort4 wv;
      wv.x = f2bf(acc.x); wv.y = f2bf(acc.y); wv.z = f2bf(acc.z); wv.w = f2bf(acc.w);
      ((ushort4*)KVp)[idx] = wv;
      acc.x += bf2f(t.x); acc.y += bf2f(t.y); acc.z += bf2f(t.z); acc.w += bf2f(t.w);
    }
    ((float4*)kv_out)[bh * 4368 + e4] = acc;
  } else {
    int e = gid - 1092 * 256;
    if (e < 17472) {
      int bh = e / DFEAT, r = e - bh * DFEAT;
      float acc = kst0[e];
      size_t base = (size_t)bh * NC * DFEAT + r;
#pragma unroll
      for (int ck = 0; ck < NC; ck++) {
        size_t idx = base + (size_t)ck * DFEAT;
        unsigned short t = kstc[idx];
        kstp[idx] = f2bf(acc);
        acc += bf2f(t);
      }
      kst_out[e] = acc;
    }
  }
}

// ------------------------------ phase C (MFMA) -----------------------------
__global__ __launch_bounds__(256, 2) void phaseC_mfma(
    const unsigned short* __restrict__ qlin, const unsigned short* __restrict__ klin,
    const unsigned short* __restrict__ vb, const unsigned short* __restrict__ KVp,
    const unsigned short* __restrict__ kstp, unsigned short* __restrict__ outs) {
  __shared__ unsigned short q_b[128 * 16];
  __shared__ unsigned short k_b[128 * 16];
  __shared__ unsigned short S_l[128 * 128];
  __shared__ unsigned short Af[128 * 32];
  __shared__ unsigned short Bf[80 * 32];
  unsigned short* vstage = Af;
  const int tid = threadIdx.x, lane = tid & 63, w = tid >> 6;
  const int m15 = lane & 15, quad = lane >> 4;
  const int bh = blockIdx.x >> 4, ck = blockIdx.x & 15;
  const int b = bh >> 4, hh = bh & 15;
  const int t0 = ck * CHUNK;
  const unsigned short* KVb = KVp + ((size_t)bh * NC + ck) * (DFEAT * 64);
  const unsigned short* kstb = kstp + ((size_t)bh * NC + ck) * DFEAT;
  {
    int r = tid >> 1, half = tid & 1;
    *(short8*)&q_b[r * 16 + half * 8] =
        *(const short8*)(qlin + ((size_t)(b * LL + t0 + r)) * 256 + hh * 16 + half * 8);
    *(short8*)&k_b[r * 16 + half * 8] =
        *(const short8*)(klin + ((size_t)(b * LL + t0 + r)) * 256 + hh * 16 + half * 8);
  }
  __syncthreads();
  float qv[16];
  {
    int r = tid >> 1;
    short8 q0 = *(const short8*)&q_b[r * 16];
    short8 q1 = *(const short8*)&q_b[r * 16 + 8];
#pragma unroll
    for (int j = 0; j < 8; j++) {
      qv[j] = bf2f(((unsigned short*)&q0)[j]);
      qv[8 + j] = bf2f(((unsigned short*)&q1)[j]);
    }
  }
  f32x4 acc[2][5] = {};
  for (int ks = 0; ks < 9; ++ks) {
    int fs = ks * 32;
    {
      int r = tid >> 1;
#pragma unroll
      for (int gg = 0; gg < 2; gg++) {
        int g = (tid & 1) * 2 + gg;
        short8 vv;
        unsigned short* pv = (unsigned short*)&vv;
#pragma unroll
        for (int j = 0; j < 8; j++) {
          int f = fs + g * 8 + j;
          float val;
          if (f == 0) val = 1.0f;
          else if (f < 17) val = qv[f - 1] * 0.5f;
          else if (f < DFEAT) {
            int ij = f - 17;
            val = qv[ij >> 4] * qv[ij & 15] * 0.17677669529663687f;
          } else val = 0.0f;
          pv[j] = f2bf(val);
        }
        int p = g ^ (r & 3);
        *(short8*)&Af[r * 32 + p * 8] = vv;
      }
    }
    for (int id = tid; id < 320; id += 256) {
      int c = id >> 2, g = id & 3;
      short8 vv;
      unsigned short* pv = (unsigned short*)&vv;
#pragma unroll
      for (int j = 0; j < 8; j++) {
        int f = fs + g * 8 + j;
        unsigned short val = 0;
        if (f < DFEAT) {
          if (c < 64) val = KVb[(size_t)f * 64 + c];
          else if (c == 64) val = kstb[f];
        }
        pv[j] = val;
      }
      int p = g ^ (c & 3);
      *(short8*)&Bf[c * 32 + p * 8] = vv;
    }
    __syncthreads();
    short8 aF[2], bF[5];
#pragma unroll
    for (int mi = 0; mi < 2; mi++) {
      int r = w * 32 + mi * 16 + m15;
      int p = quad ^ (r & 3);
      aF[mi] = *(const short8*)&Af[r * 32 + p * 8];
    }
#pragma unroll
    for (int ni = 0; ni < 5; ni++) {
      int c = ni * 16 + m15;
      int p = quad ^ (c & 3);
      bF[ni] = *(const short8*)&Bf[c * 32 + p * 8];
    }
#pragma unroll
    for (int mi = 0; mi < 2; mi++)
#pragma unroll
      for (int ni = 0; ni < 5; ni++)
        acc[mi][ni] = __builtin_amdgcn_mfma_f32_16x16x32_bf16(
            aF[mi], bF[ni], acc[mi][ni], 0, 0, 0);
    __syncthreads();
  }
  {
    short8 z = {0, 0, 0, 0, 0, 0, 0, 0};
    short8 bU[8];
#pragma unroll
    for (int sn = 0; sn < 8; sn++) {
      int s = sn * 16 + m15;
      bU[sn] = (quad < 2) ? *(const short8*)&k_b[s * 16 + quad * 8] : z;
    }
#pragma unroll
    for (int mi = 0; mi < 2; mi++) {
      int t_row = w * 32 + mi * 16 + m15;
      short8 aU = (quad < 2) ? *(const short8*)&q_b[t_row * 16 + quad * 8] : z;
#pragma unroll
      for (int sn = 0; sn < 8; sn++) {
        f32x4 zz = {0.f, 0.f, 0.f, 0.f};
        f32x4 u = __builtin_amdgcn_mfma_f32_16x16x32_bf16(aU, bU[sn], zz, 0, 0, 0);
        int s = sn * 16 + m15;
        int gRow = s >> 3;
#pragma unroll
        for (int rr = 0; rr < 4; rr++) {
          int t = w * 32 + mi * 16 + quad * 4 + rr;
          float uu = u[rr];
          float sv = (s <= t) ? fmaf(uu, fmaf(uu, 0.03125f, 0.25f), 1.0f) : 0.0f;
          int p = gRow ^ (t & 7);
          S_l[t * 128 + p * 8 + (s & 7)] = f2bf(sv);
        }
      }
    }
  }
  for (int ks = 0; ks < 4; ++ks) {
    {
      int sl = tid >> 3, c8 = (tid & 7) * 8;
      *(short8*)&vstage[sl * 64 + c8] =
          *(const short8*)(vb + ((size_t)(b * LL + t0 + ks * 32 + sl)) * DD + hh * 64 + c8);
    }
    __syncthreads();
    for (int id = tid; id < 320; id += 256) {
      int c = id >> 2, g = id & 3;
      short8 vv;
      unsigned short* pv = (unsigned short*)&vv;
#pragma unroll
      for (int j = 0; j < 8; j++) {
        int sl = g * 8 + j;
        pv[j] = (c < 64) ? vstage[sl * 64 + c]
                         : (c == 64 ? (unsigned short)0x3F80 : (unsigned short)0);
      }
      int p = g ^ (c & 3);
      *(short8*)&Bf[c * 32 + p * 8] = vv;
    }
    __syncthreads();
    short8 aF[2], bF[5];
#pragma unroll
    for (int mi = 0; mi < 2; mi++) {
      int t = w * 32 + mi * 16 + m15;
      int p = (ks * 4 + quad) ^ (t & 7);
      aF[mi] = *(const short8*)&S_l[t * 128 + p * 8];
    }
#pragma unroll
    for (int ni = 0; ni < 5; ni++) {
      int c = ni * 16 + m15;
      int p = quad ^ (c & 3);
      bF[ni] = *(const short8*)&Bf[c * 32 + p * 8];
    }
#pragma unroll
    for (int mi = 0; mi < 2; mi++)
#pragma unroll
      for (int ni = 0; ni < 5; ni++)
        acc[mi][ni] = __builtin_amdgcn_mfma_f32_16x16x32_bf16(
            aF[mi], bF[ni], acc[mi][ni], 0, 0, 0);
    __syncthreads();
  }
#pragma unroll
  for (int mi = 0; mi < 2; mi++) {
#pragma unroll
    for (int rr = 0; rr < 4; rr++) {
      float den = __shfl(acc[mi][4][rr], (lane & 48));
      float inv = 1.0f / (den + 1e-6f);
      int t = w * 32 + mi * 16 + quad * 4 + rr;
      unsigned short* op = outs + ((size_t)(b * LL + t0 + t)) * DD + hh * 64;
#pragma unroll
      for (int ni = 0; ni < 4; ni++)
        op[ni * 16 + m15] = f2bf(acc[mi][ni][rr] * inv);
    }
  }
}

// --------------------------- last-row k2/v2 --------------------------------
__global__ __launch_bounds__(256) void lastrow_qkv(
    const float* __restrict__ x1,
    const float* __restrict__ Wk, const float* __restrict__ bk,
    const float* __restrict__ Wv, const float* __restrict__ bv,
    float* __restrict__ klast, float* __restrict__ vlast) {
  int gid = blockIdx.x * 256 + threadIdx.x;
  int which = gid >> 12;
  int b = (gid >> 10) & 3;
  int n = gid & 1023;
  const float* W = which ? Wv : Wk;
  const float* xr = x1 + ((size_t)(b * LL + LL - 1)) * DD;
  float s = 0.f;
  for (int k = 0; k < 1024; k++) s = fmaf(xr[k], W[(size_t)k * 1024 + n], s);
  s += which ? bv[n] : bk[n];
  (which ? vlast : klast)[b * 1024 + n] = s;
}

// --------------------------- window attention ------------------------------
__global__ __launch_bounds__(256) void window_attn(
    const float* __restrict__ q2, const float* __restrict__ klast,
    const float* __restrict__ vlast, const float* __restrict__ kbuf,
    const float* __restrict__ vbufw, unsigned short* __restrict__ win) {
  __shared__ float ukT[64][68];
  __shared__ float uvs[64][68];
  __shared__ float S[64][68];
  const int tid = threadIdx.x;
  const int bh = blockIdx.x >> 5, tile = blockIdx.x & 31;
  const int b = bh >> 4, hh = bh & 15;
#pragma unroll
  for (int p = 0; p < 4; p++) {
    int g = tid + p * 256;
    int wi = g >> 4, d4 = (g & 15) * 4;
    const float* kp = (wi < 63) ? (kbuf + ((size_t)hh * 64 + wi + 1) * 64 + d4)
                                : (klast + (size_t)b * 1024 + hh * 64 + d4);
    float4 kk = *(const float4*)kp;
    ukT[d4 + 0][wi] = kk.x; ukT[d4 + 1][wi] = kk.y;
    ukT[d4 + 2][wi] = kk.z; ukT[d4 + 3][wi] = kk.w;
    const float* vp = (wi < 63) ? (vbufw + ((size_t)hh * 64 + wi + 1) * 64 + d4)
                                : (vlast + (size_t)b * 1024 + hh * 64 + d4);
    *(float4*)&uvs[wi][d4] = *(const float4*)vp;
    const float* qp = q2 + ((size_t)(b * LL + tile * 64 + wi)) * DD + hh * 64 + d4;
    *(float4*)&S[wi][d4] = *(const float4*)qp;
  }
  __syncthreads();
  const int tx = tid & 7, ty = tid >> 3;
  const int t2 = ty * 2;
  float a[2][8] = {};
  for (int d = 0; d < 64; ++d) {
    float q0 = S[t2][d], q1 = S[t2 + 1][d];
    float4 u0 = *(const float4*)&ukT[d][tx * 8];
    float4 u1 = *(const float4*)&ukT[d][tx * 8 + 4];
    float uk8[8] = {u0.x, u0.y, u0.z, u0.w, u1.x, u1.y, u1.z, u1.w};
#pragma unroll
    for (int j = 0; j < 8; j++) {
      a[0][j] = fmaf(q0, uk8[j], a[0][j]);
      a[1][j] = fmaf(q1, uk8[j], a[1][j]);
    }
  }
  __syncthreads();
#pragma unroll
  for (int ii = 0; ii < 2; ii++) {
    *(float4*)&S[t2 + ii][tx * 8] =
        f4(a[ii][0] * 0.125f, a[ii][1] * 0.125f, a[ii][2] * 0.125f, a[ii][3] * 0.125f);
    *(float4*)&S[t2 + ii][tx * 8 + 4] =
        f4(a[ii][4] * 0.125f, a[ii][5] * 0.125f, a[ii][6] * 0.125f, a[ii][7] * 0.125f);
  }
  __syncthreads();
  if (tid < 64) {
    float v[64];
#pragma unroll
    for (int i = 0; i < 16; i++) *(float4*)&v[i * 4] = *(const float4*)&S[tid][i * 4];
    float m = v[0];
#pragma unroll
    for (int i = 1; i < 64; i++) m = fmaxf(m, v[i]);
    float l = 0.f;
#pragma unroll
    for (int i = 0; i < 64; i++) { v[i] = expf(v[i] - m); l += v[i]; }
    float inv = 1.0f / l;
#pragma unroll
    for (int i = 0; i < 16; i++)
      *(float4*)&S[tid][i * 4] =
          f4(v[i * 4] * inv, v[i * 4 + 1] * inv, v[i * 4 + 2] * inv, v[i * 4 + 3] * inv);
  }
  __syncthreads();
  float o[2][8] = {};
  for (int w = 0; w < 64; ++w) {
    float a0 = S[t2][w], a1 = S[t2 + 1][w];
    float4 x0 = *(const float4*)&uvs[w][tx * 8];
    float4 x1v = *(const float4*)&uvs[w][tx * 8 + 4];
    float uv8[8] = {x0.x, x0.y, x0.z, x0.w, x1v.x, x1v.y, x1v.z, x1v.w};
#pragma unroll
    for (int j = 0; j < 8; j++) {
      o[0][j] = fmaf(a0, uv8[j], o[0][j]);
      o[1][j] = fmaf(a1, uv8[j], o[1][j]);
    }
  }
#pragma unroll
  for (int ii = 0; ii < 2; ii++) {
    unsigned short* wp = win + ((size_t)(b * LL + tile * 64 + t2 + ii)) * DD + hh * 64 + tx * 8;
    ushort4 r0, r1;
    r0.x = f2bf(o[ii][0]); r0.y = f2bf(o[ii][1]); r0.z = f2bf(o[ii][2]); r0.w = f2bf(o[ii][3]);
    r1.x = f2bf(o[ii][4]); r1.y = f2bf(o[ii][5]); r1.z = f2bf(o[ii][6]); r1.w = f2bf(o[ii][7]);
    *(ushort4*)wp = r0;
    *(ushort4*)(wp + 4) = r1;
  }
}

// ------------------------------ LayerNorm ----------------------------------
__global__ __launch_bounds__(256) void ln_add(
    const float* __restrict__ A, const float* __restrict__ Bm,
    const float* __restrict__ gamma, const float* __restrict__ beta,
    float* __restrict__ out, unsigned short* __restrict__ outb) {
  const int row = blockIdx.x, tid = threadIdx.x;
  float4 va = ((const float4*)(A + (size_t)row * DD))[tid];
  float4 vb = ((const float4*)(Bm + (size_t)row * DD))[tid];
  float4 s4 = f4(va.x + vb.x, va.y + vb.y, va.z + vb.z, va.w + vb.w);
  float s = s4.x + s4.y + s4.z + s4.w;
  float ss = s4.x * s4.x + s4.y * s4.y + s4.z * s4.z + s4.w * s4.w;
  for (int o = 32; o; o >>= 1) { s += __shfl_xor(s, o); ss += __shfl_xor(ss, o); }
  __shared__ float red[8];
  int wid = tid >> 6;
  if ((tid & 63) == 0) { red[wid * 2] = s; red[wid * 2 + 1] = ss; }
  __syncthreads();
  float tot = red[0] + red[2] + red[4] + red[6];
  float tots = red[1] + red[3] + red[5] + red[7];
  float mu = tot * (1.0f / 1024.0f);
  float var = tots * (1.0f / 1024.0f) - mu * mu;
  float rstd = rsqrtf(var + 1e-5f);
  float4 g = ((const float4*)gamma)[tid];
  float4 be = ((const float4*)beta)[tid];
  float4 o = f4((s4.x - mu) * rstd * g.x + be.x, (s4.y - mu) * rstd * g.y + be.y,
                (s4.z - mu) * rstd * g.z + be.z, (s4.w - mu) * rstd * g.w + be.w);
  ((float4*)(out + (size_t)row * DD))[tid] = o;
  if (outb) {
    ushort4 r;
    r.x = f2bf(o.x); r.y = f2bf(o.y); r.z = f2bf(o.z); r.w = f2bf(o.w);
    ((ushort4*)(outb + (size_t)row * DD))[tid] = r;
  }
}

// ------------------------------ launch -------------------------------------
extern "C" void kernel_launch(void* const* d_in, const int* in_sizes, int n_in,
                              void* d_out, int out_size, void* d_ws, size_t ws_size,
                              hipStream_t stream) {
  (void)in_sizes; (void)n_in; (void)out_size; (void)ws_size;
  const float* x      = (const float*)d_in[0];
  const float* kv0    = (const float*)d_in[1];
  const float* kst0   = (const float*)d_in[2];
  const float* kbuf   = (const float*)d_in[3];
  const float* vbufw  = (const float*)d_in[4];
  const float* Wq_lin = (const float*)d_in[5];
  const float* bq_lin = (const float*)d_in[6];
  const float* Wk_lin = (const float*)d_in[7];
  const float* bk_lin = (const float*)d_in[8];
  const float* Wv_lin = (const float*)d_in[9];
  const float* bv_lin = (const float*)d_in[10];
  const float* Wo_lin = (const float*)d_in[11];
  const float* bo_lin = (const float*)d_in[12];
  const float* Wq     = (const float*)d_in[13];
  const float* bq     = (const float*)d_in[14];
  const float* Wk     = (const float*)d_in[15];
  const float* bk     = (const float*)d_in[16];
  const float* Wv     = (const float*)d_in[17];
  const float* bv     = (const float*)d_in[18];
  const float* Wo     = (const float*)d_in[19];
  const float* bo     = (const float*)d_in[20];
  const float* gamma  = (const float*)d_in[21];
  const float* beta   = (const float*)d_in[22];

  float* out = (float*)d_out;
  float* kv_out  = out + 8388608;
  float* kst_out = out + 8388608 + 1118208;

  float* ws = (float*)d_ws;
  const size_t MF = 1024 * 1024;
  // timeline-packed layout (float offsets)
  unsigned short* qlin_b = (unsigned short*)(ws);              // [0,1) MF
  unsigned short* klin_b = (unsigned short*)(ws + 1 * MF);     // [1,2)
  unsigned short* v_b    = (unsigned short*)(ws + 2 * MF);     // [2,6)
  unsigned short* KVc_bf = (unsigned short*)(ws + 6 * MF);     // 17891328 us -> [6,14.53)
  unsigned short* kstc_bf = (unsigned short*)(ws + 15237120);  // 279552 us
  unsigned short* KVp    = (unsigned short*)(ws + 15376896);   // [14.67,23.2)
  unsigned short* kstp   = (unsigned short*)(ws + 24322560);   // to 24462336
  unsigned short* x_bf   = (unsigned short*)(ws + 24 * MF);    // [24,28), dead pre-phaseA
  unsigned short* outs_bf = (unsigned short*)(ws + 6 * MF);    // [6,8)   (KVc_bf dead)
  float* tmp  = ws + 8 * MF;                                   // [8,16)  (KVp dead after phaseC)
  float* x1   = ws + 16 * MF;                                  // [16,24)
  unsigned short* x1b = (unsigned short*)(ws + 24 * MF);       // [24,26) (x_bf dead)
  float* q2   = ws;                                            // [0,8)   (qkv_b/outs_bf dead)
  unsigned short* winb = (unsigned short*)(ws + 26 * MF);      // [26,30)
  float* tmp2 = ws + 6 * MF;                                   // [6,14)  (q2/tmp dead)
  unsigned short* WtQL = (unsigned short*)(ws + 33 * MF);      // weights [33,35.25)
  unsigned short* WtKL = WtQL + 262144;
  unsigned short* WtVL = WtQL + 524288;
  unsigned short* WtO1 = WtQL + 1572864;
  unsigned short* WtQ2 = WtQL + 2621440;
  unsigned short* WtO2 = WtQL + 3670016;
  float* klast = ws + 37224448;                                // 35.5 MF
  float* vlast = klast + 4096;

  dim3 blk(256);
  cast_bf16<<<8192, blk, 0, stream>>>(x, x_bf, 2097152);
  castT<<<dim3(16, 4), blk, 0, stream>>>(Wq_lin, WtQL, 1024, 256);
  castT<<<dim3(16, 4), blk, 0, stream>>>(Wk_lin, WtKL, 1024, 256);
  castT<<<dim3(16, 16), blk, 0, stream>>>(Wv_lin, WtVL, 1024, 1024);
  castT<<<dim3(16, 16), blk, 0, stream>>>(Wo_lin, WtO1, 1024, 1024);
  castT<<<dim3(16, 16), blk, 0, stream>>>(Wq, WtQ2, 1024, 1024);
  castT<<<dim3(16, 16), blk, 0, stream>>>(Wo, WtO2, 1024, 1024);
  gemm_mfma<<<dim3(64, 2), blk, 0, stream>>>(x_bf, WtQL, bq_lin, (float*)0, qlin_b, 8192, 256, 1024);
  gemm_mfma<<<dim3(64, 2), blk, 0, stream>>>(x_bf, WtKL, bk_lin, (float*)0, klin_b, 8192, 256, 1024);
  gemm_mfma<<<dim3(64, 8), blk, 0, stream>>>(x_bf, WtVL, bv_lin, (float*)0, v_b, 8192, 1024, 1024);
  phaseA_mfma<<<1024, blk, 0, stream>>>(klin_b, v_b, KVc_bf, kstc_bf);
  phaseB2<<<1161, blk, 0, stream>>>(KVc_bf, kstc_bf, kv0, kst0, KVp, kstp, kv_out, kst_out);
  phaseC_mfma<<<1024, blk, 0, stream>>>(qlin_b, klin_b, v_b, KVp, kstp, outs_bf);
  gemm_mfma<<<dim3(64, 8), blk, 0, stream>>>(outs_bf, WtO1, bo_lin, tmp, (unsigned short*)0, 8192, 1024, 1024);
  ln_add<<<8192, blk, 0, stream>>>(x, tmp, gamma, beta, x1, x1b);
  gemm_mfma<<<dim3(64, 8), blk, 0, stream>>>(x1b, WtQ2, bq, q2, (unsigned short*)0, 8192, 1024, 1024);
  lastrow_qkv<<<32, blk, 0, stream>>>(x1, Wk, bk, Wv, bv, klast, vlast);
  window_attn<<<2048, blk, 0, stream>>>(q2, klast, vlast, kbuf, vbufw, winb);
  gemm_mfma<<<dim3(64, 8), blk, 0, stream>>>(winb, WtO2, bo, tmp2, (unsigned short*)0, 8192, 1024, 1024);
  ln_add<<<8192, blk, 0, stream>>>(x1, tmp2, gamma, beta, out, (unsigned short*)0);
}

// Round 6
// 513.349 us; speedup vs baseline: 3.4195x; 1.1163x over previous
//
#include <hip/hip_runtime.h>
#include <math.h>

// ---------------------------------------------------------------------------
// BasedBlock: B=4 L=2048 d=1024 h=16 f=16 hd=64 w=64, D=1+f+f*f=273
// Round 5: operand-marshalling rewrite of linear attention.
//   transV: V -> vT[bh][c][t]  (direct B-fragment loads for phaseA/C)
//   phaseA2: barrier-light, Kf gen per-lane from kT LDS, B from vT global,
//            writes chunk sums TRANSPOSED KVc_t[c][f] + kstc[f]
//   phaseB3: trivial coalesced scan [c][f] -> KVp_t/kstp (bf16) + fp32 outs
//   phaseC2: pass1 A = Qf gen per-lane from q_f LDS (no reg-array indexing!),
//            B = direct loads from KVp_t/kstp; intra u-MFMA -> S_l;
//            pass2 B direct from vT. LDS = q_f(8.7K)+S_l(32K).
// ---------------------------------------------------------------------------

#define LL 2048
#define DD 1024
#define DFEAT 273
#define NC 16
#define CHUNK 128

typedef __attribute__((ext_vector_type(8))) short short8;
typedef __attribute__((ext_vector_type(4))) float f32x4;

#define SQ 0.42044820762685725f   // sqrt(1/(sqrt(2)*sqrt(16))) = sqrt(0.176776...)
#define LF 1.18920711500272107f   // 0.5 / SQ

__device__ __forceinline__ float4 f4(float a, float b, float c, float d) {
  float4 r; r.x = a; r.y = b; r.z = c; r.w = d; return r;
}

__device__ __forceinline__ unsigned short f2bf(float f) {
  union { float f; unsigned u; } v; v.f = f;
  unsigned r = v.u + 0x7fffu + ((v.u >> 16) & 1u);
  return (unsigned short)(r >> 16);
}

__device__ __forceinline__ float bf2f(unsigned short u) {
  union { unsigned u; float f; } v; v.u = ((unsigned)u) << 16; return v.f;
}

// --------------------------- cast kernels ----------------------------------
__global__ __launch_bounds__(256) void cast_bf16(
    const float* __restrict__ in, unsigned short* __restrict__ o, int n4) {
  int i = blockIdx.x * 256 + threadIdx.x;
  if (i < n4) {
    float4 v = ((const float4*)in)[i];
    ushort4 r;
    r.x = f2bf(v.x); r.y = f2bf(v.y); r.z = f2bf(v.z); r.w = f2bf(v.w);
    ((ushort4*)o)[i] = r;
  }
}

// W[K][N] fp32 -> Wt[N][K] bf16
__global__ __launch_bounds__(256) void castT(
    const float* __restrict__ W, unsigned short* __restrict__ Wt, int K, int N) {
  __shared__ float t[64][65];
  int k0 = blockIdx.x * 64, n0 = blockIdx.y * 64;
  int tid = threadIdx.x;
#pragma unroll
  for (int p = 0; p < 16; p++) {
    int idx = p * 256 + tid;
    int r = idx >> 6, c = idx & 63;
    t[r][c] = W[(size_t)(k0 + r) * N + n0 + c];
  }
  __syncthreads();
#pragma unroll
  for (int p = 0; p < 16; p++) {
    int idx = p * 256 + tid;
    int rn = idx >> 6, ck = idx & 63;
    Wt[(size_t)(n0 + rn) * K + k0 + ck] = f2bf(t[ck][rn]);
  }
}

// --------------------------- MFMA GEMM -------------------------------------
__global__ __launch_bounds__(256) void gemm_mfma(
    const unsigned short* __restrict__ A, const unsigned short* __restrict__ Bt,
    const float* __restrict__ bias, float* __restrict__ C,
    unsigned short* __restrict__ Cb, int M, int N, int K) {
  __shared__ unsigned short As[128 * 64];
  __shared__ unsigned short Bs[128 * 64];
  const int tid = threadIdx.x;
  const int lane = tid & 63, w = tid >> 6;
  const int row0 = blockIdx.x * 128, col0 = blockIdx.y * 128;
  const int wm0 = (w & 1) * 64, wn0 = (w >> 1) * 64;
  const int lr = lane >> 3;
  const int gc = (lane & 7) ^ lr;
  const unsigned short* aP = A + (size_t)(row0 + w * 32 + lr) * K + gc * 8;
  const unsigned short* bP = Bt + (size_t)(col0 + w * 32 + lr) * K + gc * 8;
  unsigned short* asW = As + w * 2048;
  unsigned short* bsW = Bs + w * 2048;
  const int m15 = lane & 15, quad = lane >> 4;
  f32x4 acc[4][4] = {};
  for (int k0 = 0; k0 < K; k0 += 64) {
#pragma unroll
    for (int i = 0; i < 4; i++) {
      __builtin_amdgcn_global_load_lds(
          (const __attribute__((address_space(1))) unsigned int*)(const void*)(aP + (size_t)(i * 8) * K + k0),
          (__attribute__((address_space(3))) unsigned int*)(void*)(asW + i * 512), 16, 0, 0);
      __builtin_amdgcn_global_load_lds(
          (const __attribute__((address_space(1))) unsigned int*)(const void*)(bP + (size_t)(i * 8) * K + k0),
          (__attribute__((address_space(3))) unsigned int*)(void*)(bsW + i * 512), 16, 0, 0);
    }
    __syncthreads();
#pragma unroll
    for (int ks = 0; ks < 2; ks++) {
      short8 aF[4], bF[4];
#pragma unroll
      for (int mi = 0; mi < 4; mi++) {
        int r = wm0 + mi * 16 + m15;
        int g = (ks * 4 + quad) ^ (r & 7);
        aF[mi] = *(const short8*)(As + r * 64 + g * 8);
      }
#pragma unroll
      for (int ni = 0; ni < 4; ni++) {
        int r = wn0 + ni * 16 + m15;
        int g = (ks * 4 + quad) ^ (r & 7);
        bF[ni] = *(const short8*)(Bs + r * 64 + g * 8);
      }
#pragma unroll
      for (int mi = 0; mi < 4; mi++)
#pragma unroll
        for (int ni = 0; ni < 4; ni++)
          acc[mi][ni] = __builtin_amdgcn_mfma_f32_16x16x32_bf16(
              aF[mi], bF[ni], acc[mi][ni], 0, 0, 0);
    }
    __syncthreads();
  }
#pragma unroll
  for (int mi = 0; mi < 4; mi++)
#pragma unroll
    for (int ni = 0; ni < 4; ni++) {
      int col = col0 + wn0 + ni * 16 + m15;
      float bb = bias[col];
#pragma unroll
      for (int r = 0; r < 4; r++) {
        int row = row0 + wm0 + mi * 16 + quad * 4 + r;
        float val = acc[mi][ni][r] + bb;
        if (Cb) Cb[(size_t)row * N + col] = f2bf(val);
        else C[(size_t)row * N + col] = val;
      }
    }
}

// ------------------------------ transV -------------------------------------
// v_b[t][h*64+c] -> vT[bh][c][t]
__global__ __launch_bounds__(256) void transV(
    const unsigned short* __restrict__ v_b, unsigned short* __restrict__ vT) {
  __shared__ unsigned short Tv[64][72];
  const int blk = blockIdx.x;
  const int bh = blk >> 5, tt = blk & 31;
  const int b = bh >> 4, hh = bh & 15;
  const int t0 = tt * 64;
  const int tid = threadIdx.x;
  {
    int t = tid >> 2, cs = tid & 3;
    const unsigned short* p = v_b + ((size_t)(b * LL + t0 + t)) * DD + hh * 64 + cs * 16;
    *(short8*)&Tv[t][cs * 16] = *(const short8*)p;
    *(short8*)&Tv[t][cs * 16 + 8] = *(const short8*)(p + 8);
  }
  __syncthreads();
  {
    int c = tid & 63, ts = tid >> 6;
    unsigned short vals[16];
#pragma unroll
    for (int j = 0; j < 16; j++) vals[j] = Tv[ts * 16 + j][c];
    unsigned short* op = vT + ((size_t)bh * 64 + c) * LL + t0 + ts * 16;
    *(short8*)op = *(short8*)&vals[0];
    *(short8*)(op + 8) = *(short8*)&vals[8];
  }
}

// ------------------------------ phase A ------------------------------------
// KVc_t[bh][ck][c][f] = sum_t Kf[t][f] V[t][c] (bf16); kstc[bh][ck][f].
__global__ __launch_bounds__(256) void phaseA2(
    const unsigned short* __restrict__ klin, const unsigned short* __restrict__ vT,
    unsigned short* __restrict__ KVc_t, unsigned short* __restrict__ kstc) {
  __shared__ unsigned short kT[16][136];   // kT[i][t] = bf16(k[t][i]*SQ)
  const int tid = threadIdx.x, lane = tid & 63, w = tid >> 6;
  const int m15 = lane & 15, quad = lane >> 4;
  const int bh = blockIdx.x >> 4, ck = blockIdx.x & 15;
  const int b = bh >> 4, hh = bh & 15;
  const int t0 = ck * CHUNK;
  {
    int r = tid >> 1, half = tid & 1;
    short8 kv = *(const short8*)(klin + ((size_t)(b * LL + t0 + r)) * 256 + hh * 16 + half * 8);
#pragma unroll
    for (int j = 0; j < 8; j++)
      kT[half * 8 + j][r] = f2bf(bf2f(((unsigned short*)&kv)[j]) * SQ);
  }
  __syncthreads();
  short8 ones8 = {16256, 16256, 16256, 16256, 16256, 16256, 16256, 16256};
  short8 zer8 = {0, 0, 0, 0, 0, 0, 0, 0};
  f32x4 acc[5][5] = {};
  const unsigned short* vbase = vT + (size_t)bh * 64 * LL + t0;
#pragma unroll
  for (int ks = 0; ks < 4; ++ks) {
    const int tt = ks * 32 + quad * 8;
    short8 aF[5], bF[5];
#pragma unroll
    for (int mi = 0; mi < 5; mi++) {
      int r = (w * 5 + mi) * 16 + m15;
      short8 av;
      unsigned short* pv = (unsigned short*)&av;
      if (r == 0) {
        av = ones8;
      } else if (r < 17) {
        short8 k1 = *(const short8*)&kT[r - 1][tt];
#pragma unroll
        for (int j = 0; j < 8; j++) pv[j] = f2bf(bf2f(((unsigned short*)&k1)[j]) * LF);
      } else if (r < DFEAT) {
        int ij = r - 17;
        short8 k1 = *(const short8*)&kT[ij >> 4][tt];
        short8 k2 = *(const short8*)&kT[ij & 15][tt];
#pragma unroll
        for (int j = 0; j < 8; j++)
          pv[j] = f2bf(bf2f(((unsigned short*)&k1)[j]) * bf2f(((unsigned short*)&k2)[j]));
      } else {
        av = zer8;
      }
      aF[mi] = av;
    }
#pragma unroll
    for (int ni = 0; ni < 4; ni++)
      bF[ni] = *(const short8*)(vbase + ((size_t)(ni * 16 + m15)) * LL + tt);
    bF[4] = (m15 == 0) ? ones8 : zer8;
#pragma unroll
    for (int mi = 0; mi < 5; mi++)
#pragma unroll
      for (int ni = 0; ni < 5; ni++)
        acc[mi][ni] = __builtin_amdgcn_mfma_f32_16x16x32_bf16(
            aF[mi], bF[ni], acc[mi][ni], 0, 0, 0);
  }
  const size_t cb = ((size_t)bh * NC + ck) * (64 * 288);
  const size_t kb = ((size_t)bh * NC + ck) * 288;
#pragma unroll
  for (int mi = 0; mi < 5; mi++) {
    int fb = (w * 5 + mi) * 16 + quad * 4;
    if (fb < 288) {
#pragma unroll
      for (int ni = 0; ni < 4; ni++) {
        int c = ni * 16 + m15;
        ushort4 sv;
        sv.x = f2bf(acc[mi][ni][0]); sv.y = f2bf(acc[mi][ni][1]);
        sv.z = f2bf(acc[mi][ni][2]); sv.w = f2bf(acc[mi][ni][3]);
        *(ushort4*)(KVc_t + cb + (size_t)c * 288 + fb) = sv;
      }
      if (m15 == 0) {
        ushort4 sv;
        sv.x = f2bf(acc[mi][4][0]); sv.y = f2bf(acc[mi][4][1]);
        sv.z = f2bf(acc[mi][4][2]); sv.w = f2bf(acc[mi][4][3]);
        *(ushort4*)(kstc + kb + fb) = sv;
      }
    }
  }
}

// ------------------------------ phase B ------------------------------------
// Blocks [0,576): KV scan (thread per (bh,c,f8)); [576,585): kst scan.
__global__ __launch_bounds__(256) void phaseB3(
    const unsigned short* __restrict__ KVc_t, const unsigned short* __restrict__ kstc,
    const float* __restrict__ kv0, const float* __restrict__ kst0,
    unsigned short* __restrict__ KVp_t, unsigned short* __restrict__ kstp,
    float* __restrict__ kv_out, float* __restrict__ kst_out) {
  const int tid = threadIdx.x;
  if (blockIdx.x < 576) {
    int gid = blockIdx.x * 256 + tid;
    int bh = gid / 2304, rem = gid - bh * 2304;
    int c = rem / 36, fg = rem - c * 36;
    int f0 = fg * 8;
    float acc[8];
#pragma unroll
    for (int j = 0; j < 8; j++) {
      int f = f0 + j;
      acc[j] = (f < DFEAT) ? kv0[((size_t)bh * DFEAT + f) * 64 + c] : 0.0f;
    }
    size_t base = ((size_t)bh * NC) * (64 * 288) + (size_t)c * 288 + f0;
    for (int ck = 0; ck < NC; ck++) {
      size_t idx = base + (size_t)ck * (64 * 288);
      short8 t = *(const short8*)(KVc_t + idx);
      unsigned short ov[8];
#pragma unroll
      for (int j = 0; j < 8; j++) {
        ov[j] = f2bf(acc[j]);
        acc[j] += bf2f(((unsigned short*)&t)[j]);
      }
      *(short8*)(KVp_t + idx) = *(short8*)ov;
    }
#pragma unroll
    for (int j = 0; j < 8; j++) {
      int f = f0 + j;
      if (f < DFEAT) kv_out[((size_t)bh * DFEAT + f) * 64 + c] = acc[j];
    }
  } else {
    int idx0 = (blockIdx.x - 576) * 256 + tid;   // 0..2303
    int bh = idx0 / 36, fg = idx0 - bh * 36;
    int f0 = fg * 8;
    float acc[8];
#pragma unroll
    for (int j = 0; j < 8; j++) {
      int f = f0 + j;
      acc[j] = (f < DFEAT) ? kst0[bh * DFEAT + f] : 0.0f;
    }
    for (int ck = 0; ck < NC; ck++) {
      size_t idx = ((size_t)bh * NC + ck) * 288 + f0;
      short8 t = *(const short8*)(kstc + idx);
      unsigned short ov[8];
#pragma unroll
      for (int j = 0; j < 8; j++) {
        ov[j] = f2bf(acc[j]);
        acc[j] += bf2f(((unsigned short*)&t)[j]);
      }
      *(short8*)(kstp + idx) = *(short8*)ov;
    }
#pragma unroll
    for (int j = 0; j < 8; j++) {
      int f = f0 + j;
      if (f < DFEAT) kst_out[bh * DFEAT + f] = acc[j];
    }
  }
}

// ------------------------------ phase C ------------------------------------
__global__ __launch_bounds__(256) void phaseC2(
    const unsigned short* __restrict__ qlin, const unsigned short* __restrict__ klin,
    const unsigned short* __restrict__ vT, const unsigned short* __restrict__ KVp_t,
    const unsigned short* __restrict__ kstp, unsigned short* __restrict__ outs) {
  __shared__ float q_f[128][17];           // 8.7 KB, q*SQ
  __shared__ unsigned short S_l[128 * 128]; // 32 KB
  const int tid = threadIdx.x, lane = tid & 63, w = tid >> 6;
  const int m15 = lane & 15, quad = lane >> 4;
  const int bh = blockIdx.x >> 4, ck = blockIdx.x & 15;
  const int b = bh >> 4, hh = bh & 15;
  const int t0 = ck * CHUNK;
  const unsigned short* qbase = qlin + ((size_t)(b * LL + t0)) * 256 + hh * 16;
  const unsigned short* kbase = klin + ((size_t)(b * LL + t0)) * 256 + hh * 16;
  {
    int r = tid >> 1, half = tid & 1;
    short8 qv = *(const short8*)(qbase + (size_t)r * 256 + half * 8);
#pragma unroll
    for (int j = 0; j < 8; j++)
      q_f[r][half * 8 + j] = bf2f(((unsigned short*)&qv)[j]) * SQ;
  }
  __syncthreads();
  short8 ones8 = {16256, 16256, 16256, 16256, 16256, 16256, 16256, 16256};
  short8 zer8 = {0, 0, 0, 0, 0, 0, 0, 0};
  const int tA0 = w * 32 + m15, tA1 = w * 32 + 16 + m15;
  f32x4 acc[2][5] = {};
  const unsigned short* KVb = KVp_t + ((size_t)(bh * NC + ck)) * (64 * 288);
  const unsigned short* kstb = kstp + ((size_t)(bh * NC + ck)) * 288;
  // ---- pass 1: inter (Qf @ KV'), barrier-free ----
#pragma unroll
  for (int ks = 0; ks < 9; ++ks) {
    const int fs = ks * 32 + quad * 8;
    short8 aF[2], bF[5];
#pragma unroll
    for (int mi = 0; mi < 2; mi++) {
      const float* qr = &q_f[mi ? tA1 : tA0][0];
      unsigned short pv[8];
#pragma unroll
      for (int j = 0; j < 8; j++) {
        int f = fs + j;
        float val;
        if (f == 0) val = 1.0f;
        else if (f < 17) val = qr[f - 1] * LF;
        else if (f < DFEAT) val = qr[(f - 17) >> 4] * qr[(f - 17) & 15];
        else val = 0.0f;
        pv[j] = f2bf(val);
      }
      aF[mi] = *(short8*)pv;
    }
#pragma unroll
    for (int ni = 0; ni < 4; ni++)
      bF[ni] = *(const short8*)(KVb + ((size_t)(ni * 16 + m15)) * 288 + fs);
    bF[4] = (m15 == 0) ? *(const short8*)(kstb + fs) : zer8;
#pragma unroll
    for (int mi = 0; mi < 2; mi++)
#pragma unroll
      for (int ni = 0; ni < 5; ni++)
        acc[mi][ni] = __builtin_amdgcn_mfma_f32_16x16x32_bf16(
            aF[mi], bF[ni], acc[mi][ni], 0, 0, 0);
  }
  // ---- intra: u = q@k^T (K=16 pad 32) -> poly/mask -> S_l ----
  {
    short8 aU[2], bU[8];
    aU[0] = (quad < 2) ? *(const short8*)(qbase + (size_t)tA0 * 256 + quad * 8) : zer8;
    aU[1] = (quad < 2) ? *(const short8*)(qbase + (size_t)tA1 * 256 + quad * 8) : zer8;
#pragma unroll
    for (int sn = 0; sn < 8; sn++) {
      int s = sn * 16 + m15;
      bU[sn] = (quad < 2) ? *(const short8*)(kbase + (size_t)s * 256 + quad * 8) : zer8;
    }
#pragma unroll
    for (int mi = 0; mi < 2; mi++) {
#pragma unroll
      for (int sn = 0; sn < 8; sn++) {
        f32x4 zz = {0.f, 0.f, 0.f, 0.f};
        f32x4 u = __builtin_amdgcn_mfma_f32_16x16x32_bf16(aU[mi], bU[sn], zz, 0, 0, 0);
        int s = sn * 16 + m15;
        int gRow = s >> 3;
#pragma unroll
        for (int rr = 0; rr < 4; rr++) {
          int t = w * 32 + mi * 16 + quad * 4 + rr;
          float uu = u[rr];
          float sv = (s <= t) ? fmaf(uu, fmaf(uu, 0.03125f, 0.25f), 1.0f) : 0.0f;
          int p = gRow ^ (t & 7);
          S_l[t * 128 + p * 8 + (s & 7)] = f2bf(sv);
        }
      }
    }
  }
  __syncthreads();
  // ---- pass 2: S @ V' (B direct from vT), barrier-free ----
  const unsigned short* vbase = vT + (size_t)bh * 64 * LL + t0;
#pragma unroll
  for (int ks = 0; ks < 4; ++ks) {
    const int tt = ks * 32 + quad * 8;
    short8 aF[2], bF[5];
#pragma unroll
    for (int mi = 0; mi < 2; mi++) {
      int t = w * 32 + mi * 16 + m15;
      int p = (ks * 4 + quad) ^ (t & 7);
      aF[mi] = *(const short8*)&S_l[t * 128 + p * 8];
    }
#pragma unroll
    for (int ni = 0; ni < 4; ni++)
      bF[ni] = *(const short8*)(vbase + ((size_t)(ni * 16 + m15)) * LL + tt);
    bF[4] = (m15 == 0) ? ones8 : zer8;
#pragma unroll
    for (int mi = 0; mi < 2; mi++)
#pragma unroll
      for (int ni = 0; ni < 5; ni++)
        acc[mi][ni] = __builtin_amdgcn_mfma_f32_16x16x32_bf16(
            aF[mi], bF[ni], acc[mi][ni], 0, 0, 0);
  }
  // ---- epilogue ----
#pragma unroll
  for (int mi = 0; mi < 2; mi++) {
#pragma unroll
    for (int rr = 0; rr < 4; rr++) {
      float den = __shfl(acc[mi][4][rr], (lane & 48));
      float inv = 1.0f / (den + 1e-6f);
      int t = w * 32 + mi * 16 + quad * 4 + rr;
      unsigned short* op = outs + ((size_t)(b * LL + t0 + t)) * DD + hh * 64;
#pragma unroll
      for (int ni = 0; ni < 4; ni++)
        op[ni * 16 + m15] = f2bf(acc[mi][ni][rr] * inv);
    }
  }
}

// --------------------------- last-row k2/v2 --------------------------------
__global__ __launch_bounds__(256) void lastrow_qkv(
    const float* __restrict__ x1,
    const float* __restrict__ Wk, const float* __restrict__ bk,
    const float* __restrict__ Wv, const float* __restrict__ bv,
    float* __restrict__ klast, float* __restrict__ vlast) {
  int gid = blockIdx.x * 256 + threadIdx.x;
  int which = gid >> 12;
  int b = (gid >> 10) & 3;
  int n = gid & 1023;
  const float* W = which ? Wv : Wk;
  const float* xr = x1 + ((size_t)(b * LL + LL - 1)) * DD;
  float s = 0.f;
  for (int k = 0; k < 1024; k++) s = fmaf(xr[k], W[(size_t)k * 1024 + n], s);
  s += which ? bv[n] : bk[n];
  (which ? vlast : klast)[b * 1024 + n] = s;
}

// --------------------------- window attention ------------------------------
__global__ __launch_bounds__(256) void window_attn(
    const float* __restrict__ q2, const float* __restrict__ klast,
    const float* __restrict__ vlast, const float* __restrict__ kbuf,
    const float* __restrict__ vbufw, unsigned short* __restrict__ win) {
  __shared__ float ukT[64][68];
  __shared__ float uvs[64][68];
  __shared__ float S[64][68];
  const int tid = threadIdx.x;
  const int bh = blockIdx.x >> 5, tile = blockIdx.x & 31;
  const int b = bh >> 4, hh = bh & 15;
#pragma unroll
  for (int p = 0; p < 4; p++) {
    int g = tid + p * 256;
    int wi = g >> 4, d4 = (g & 15) * 4;
    const float* kp = (wi < 63) ? (kbuf + ((size_t)hh * 64 + wi + 1) * 64 + d4)
                                : (klast + (size_t)b * 1024 + hh * 64 + d4);
    float4 kk = *(const float4*)kp;
    ukT[d4 + 0][wi] = kk.x; ukT[d4 + 1][wi] = kk.y;
    ukT[d4 + 2][wi] = kk.z; ukT[d4 + 3][wi] = kk.w;
    const float* vp = (wi < 63) ? (vbufw + ((size_t)hh * 64 + wi + 1) * 64 + d4)
                                : (vlast + (size_t)b * 1024 + hh * 64 + d4);
    *(float4*)&uvs[wi][d4] = *(const float4*)vp;
    const float* qp = q2 + ((size_t)(b * LL + tile * 64 + wi)) * DD + hh * 64 + d4;
    *(float4*)&S[wi][d4] = *(const float4*)qp;
  }
  __syncthreads();
  const int tx = tid & 7, ty = tid >> 3;
  const int t2 = ty * 2;
  float a[2][8] = {};
  for (int d = 0; d < 64; ++d) {
    float q0 = S[t2][d], q1 = S[t2 + 1][d];
    float4 u0 = *(const float4*)&ukT[d][tx * 8];
    float4 u1 = *(const float4*)&ukT[d][tx * 8 + 4];
    float uk8[8] = {u0.x, u0.y, u0.z, u0.w, u1.x, u1.y, u1.z, u1.w};
#pragma unroll
    for (int j = 0; j < 8; j++) {
      a[0][j] = fmaf(q0, uk8[j], a[0][j]);
      a[1][j] = fmaf(q1, uk8[j], a[1][j]);
    }
  }
  __syncthreads();
#pragma unroll
  for (int ii = 0; ii < 2; ii++) {
    *(float4*)&S[t2 + ii][tx * 8] =
        f4(a[ii][0] * 0.125f, a[ii][1] * 0.125f, a[ii][2] * 0.125f, a[ii][3] * 0.125f);
    *(float4*)&S[t2 + ii][tx * 8 + 4] =
        f4(a[ii][4] * 0.125f, a[ii][5] * 0.125f, a[ii][6] * 0.125f, a[ii][7] * 0.125f);
  }
  __syncthreads();
  if (tid < 64) {
    float v[64];
#pragma unroll
    for (int i = 0; i < 16; i++) *(float4*)&v[i * 4] = *(const float4*)&S[tid][i * 4];
    float m = v[0];
#pragma unroll
    for (int i = 1; i < 64; i++) m = fmaxf(m, v[i]);
    float l = 0.f;
#pragma unroll
    for (int i = 0; i < 64; i++) { v[i] = expf(v[i] - m); l += v[i]; }
    float inv = 1.0f / l;
#pragma unroll
    for (int i = 0; i < 16; i++)
      *(float4*)&S[tid][i * 4] =
          f4(v[i * 4] * inv, v[i * 4 + 1] * inv, v[i * 4 + 2] * inv, v[i * 4 + 3] * inv);
  }
  __syncthreads();
  float o[2][8] = {};
  for (int w = 0; w < 64; ++w) {
    float a0 = S[t2][w], a1 = S[t2 + 1][w];
    float4 x0 = *(const float4*)&uvs[w][tx * 8];
    float4 x1v = *(const float4*)&uvs[w][tx * 8 + 4];
    float uv8[8] = {x0.x, x0.y, x0.z, x0.w, x1v.x, x1v.y, x1v.z, x1v.w};
#pragma unroll
    for (int j = 0; j < 8; j++) {
      o[0][j] = fmaf(a0, uv8[j], o[0][j]);
      o[1][j] = fmaf(a1, uv8[j], o[1][j]);
    }
  }
#pragma unroll
  for (int ii = 0; ii < 2; ii++) {
    unsigned short* wp = win + ((size_t)(b * LL + tile * 64 + t2 + ii)) * DD + hh * 64 + tx * 8;
    ushort4 r0, r1;
    r0.x = f2bf(o[ii][0]); r0.y = f2bf(o[ii][1]); r0.z = f2bf(o[ii][2]); r0.w = f2bf(o[ii][3]);
    r1.x = f2bf(o[ii][4]); r1.y = f2bf(o[ii][5]); r1.z = f2bf(o[ii][6]); r1.w = f2bf(o[ii][7]);
    *(ushort4*)wp = r0;
    *(ushort4*)(wp + 4) = r1;
  }
}

// ------------------------------ LayerNorm ----------------------------------
__global__ __launch_bounds__(256) void ln_add(
    const float* __restrict__ A, const float* __restrict__ Bm,
    const float* __restrict__ gamma, const float* __restrict__ beta,
    float* __restrict__ out, unsigned short* __restrict__ outb) {
  const int row = blockIdx.x, tid = threadIdx.x;
  float4 va = ((const float4*)(A + (size_t)row * DD))[tid];
  float4 vb = ((const float4*)(Bm + (size_t)row * DD))[tid];
  float4 s4 = f4(va.x + vb.x, va.y + vb.y, va.z + vb.z, va.w + vb.w);
  float s = s4.x + s4.y + s4.z + s4.w;
  float ss = s4.x * s4.x + s4.y * s4.y + s4.z * s4.z + s4.w * s4.w;
  for (int o = 32; o; o >>= 1) { s += __shfl_xor(s, o); ss += __shfl_xor(ss, o); }
  __shared__ float red[8];
  int wid = tid >> 6;
  if ((tid & 63) == 0) { red[wid * 2] = s; red[wid * 2 + 1] = ss; }
  __syncthreads();
  float tot = red[0] + red[2] + red[4] + red[6];
  float tots = red[1] + red[3] + red[5] + red[7];
  float mu = tot * (1.0f / 1024.0f);
  float var = tots * (1.0f / 1024.0f) - mu * mu;
  float rstd = rsqrtf(var + 1e-5f);
  float4 g = ((const float4*)gamma)[tid];
  float4 be = ((const float4*)beta)[tid];
  float4 o = f4((s4.x - mu) * rstd * g.x + be.x, (s4.y - mu) * rstd * g.y + be.y,
                (s4.z - mu) * rstd * g.z + be.z, (s4.w - mu) * rstd * g.w + be.w);
  ((float4*)(out + (size_t)row * DD))[tid] = o;
  if (outb) {
    ushort4 r;
    r.x = f2bf(o.x); r.y = f2bf(o.y); r.z = f2bf(o.z); r.w = f2bf(o.w);
    ((ushort4*)(outb + (size_t)row * DD))[tid] = r;
  }
}

// ------------------------------ launch -------------------------------------
extern "C" void kernel_launch(void* const* d_in, const int* in_sizes, int n_in,
                              void* d_out, int out_size, void* d_ws, size_t ws_size,
                              hipStream_t stream) {
  (void)in_sizes; (void)n_in; (void)out_size; (void)ws_size;
  const float* x      = (const float*)d_in[0];
  const float* kv0    = (const float*)d_in[1];
  const float* kst0   = (const float*)d_in[2];
  const float* kbuf   = (const float*)d_in[3];
  const float* vbufw  = (const float*)d_in[4];
  const float* Wq_lin = (const float*)d_in[5];
  const float* bq_lin = (const float*)d_in[6];
  const float* Wk_lin = (const float*)d_in[7];
  const float* bk_lin = (const float*)d_in[8];
  const float* Wv_lin = (const float*)d_in[9];
  const float* bv_lin = (const float*)d_in[10];
  const float* Wo_lin = (const float*)d_in[11];
  const float* bo_lin = (const float*)d_in[12];
  const float* Wq     = (const float*)d_in[13];
  const float* bq     = (const float*)d_in[14];
  const float* Wk     = (const float*)d_in[15];
  const float* bk     = (const float*)d_in[16];
  const float* Wv     = (const float*)d_in[17];
  const float* bv     = (const float*)d_in[18];
  const float* Wo     = (const float*)d_in[19];
  const float* bo     = (const float*)d_in[20];
  const float* gamma  = (const float*)d_in[21];
  const float* beta   = (const float*)d_in[22];

  float* out = (float*)d_out;
  float* kv_out  = out + 8388608;
  float* kst_out = out + 8388608 + 1118208;

  float* ws = (float*)d_ws;
  const size_t MF = 1024 * 1024;
  // float-offset layout (lifetimes in comments)
  unsigned short* qlin_b = (unsigned short*)(ws);              // [0,1)  until phaseC
  unsigned short* klin_b = (unsigned short*)(ws + 1 * MF);     // [1,2)  until phaseC
  unsigned short* v_b    = (unsigned short*)(ws + 2 * MF);     // [2,6)  until transV
  unsigned short* vT     = (unsigned short*)(ws + 6 * MF);     // [6,10) until phaseC
  unsigned short* KVc_t  = (unsigned short*)(ws + 10 * MF);    // [10,19) A->B
  unsigned short* kstc   = (unsigned short*)(ws + 19 * MF);    // [19,19.15) A->B
  unsigned short* KVp_t  = (unsigned short*)(ws + 20 * MF);    // [20,29) B->C
  unsigned short* kstp   = (unsigned short*)(ws + 29 * MF);    // [29,29.15) B->C
  unsigned short* x_bf   = (unsigned short*)(ws + 30 * MF);    // [30,34) until v GEMM
  unsigned short* outs_bf = (unsigned short*)(ws + 2 * MF);    // [2,6)  C->O1 (v_b dead)
  float* tmp  = ws + 10 * MF;                                  // [10,18) O1->ln (KVc_t dead)
  float* x1   = ws + 20 * MF;                                  // [20,28) (KVp_t dead)
  unsigned short* x1b = (unsigned short*)(ws + 30 * MF);       // [30,32) (x_bf dead)
  float* q2   = ws;                                            // [0,8)  (qlin/klin/outs/vT dead)
  unsigned short* winb = (unsigned short*)(ws + 8 * MF);       // [8,12) (tmp dead)
  float* tmp2 = ws + 12 * MF;                                  // [12,20)
  float* klast = ws + 34 * MF;
  float* vlast = klast + 4096;
  unsigned short* WtQL = (unsigned short*)(ws + 35 * MF);
  unsigned short* WtKL = WtQL + 262144;
  unsigned short* WtVL = WtQL + 524288;
  unsigned short* WtO1 = WtQL + 1572864;
  unsigned short* WtQ2 = WtQL + 2621440;
  unsigned short* WtO2 = WtQL + 3670016;

  dim3 blk(256);
  cast_bf16<<<8192, blk, 0, stream>>>(x, x_bf, 2097152);
  castT<<<dim3(16, 4), blk, 0, stream>>>(Wq_lin, WtQL, 1024, 256);
  castT<<<dim3(16, 4), blk, 0, stream>>>(Wk_lin, WtKL, 1024, 256);
  castT<<<dim3(16, 16), blk, 0, stream>>>(Wv_lin, WtVL, 1024, 1024);
  castT<<<dim3(16, 16), blk, 0, stream>>>(Wo_lin, WtO1, 1024, 1024);
  castT<<<dim3(16, 16), blk, 0, stream>>>(Wq, WtQ2, 1024, 1024);
  castT<<<dim3(16, 16), blk, 0, stream>>>(Wo, WtO2, 1024, 1024);
  gemm_mfma<<<dim3(64, 2), blk, 0, stream>>>(x_bf, WtQL, bq_lin, (float*)0, qlin_b, 8192, 256, 1024);
  gemm_mfma<<<dim3(64, 2), blk, 0, stream>>>(x_bf, WtKL, bk_lin, (float*)0, klin_b, 8192, 256, 1024);
  gemm_mfma<<<dim3(64, 8), blk, 0, stream>>>(x_bf, WtVL, bv_lin, (float*)0, v_b, 8192, 1024, 1024);
  transV<<<2048, blk, 0, stream>>>(v_b, vT);
  phaseA2<<<1024, blk, 0, stream>>>(klin_b, vT, KVc_t, kstc);
  phaseB3<<<585, blk, 0, stream>>>(KVc_t, kstc, kv0, kst0, KVp_t, kstp, kv_out, kst_out);
  phaseC2<<<1024, blk, 0, stream>>>(qlin_b, klin_b, vT, KVp_t, kstp, outs_bf);
  gemm_mfma<<<dim3(64, 8), blk, 0, stream>>>(outs_bf, WtO1, bo_lin, tmp, (unsigned short*)0, 8192, 1024, 1024);
  ln_add<<<8192, blk, 0, stream>>>(x, tmp, gamma, beta, x1, x1b);
  gemm_mfma<<<dim3(64, 8), blk, 0, stream>>>(x1b, WtQ2, bq, q2, (unsigned short*)0, 8192, 1024, 1024);
  lastrow_qkv<<<32, blk, 0, stream>>>(x1, Wk, bk, Wv, bv, klast, vlast);
  window_attn<<<2048, blk, 0, stream>>>(q2, klast, vlast, kbuf, vbufw, winb);
  gemm_mfma<<<dim3(64, 8), blk, 0, stream>>>(winb, WtO2, bo, tmp2, (unsigned short*)0, 8192, 1024, 1024);
  ln_add<<<8192, blk, 0, stream>>>(x1, tmp2, gamma, beta, out, (unsigned short*)0);
}